// Round 1
// baseline (4460.722 us; speedup 1.0000x reference)
//
#include <hip/hip_runtime.h>

// ---------------- problem constants (from reference) ----------------
constexpr int B_ = 2, S_ = 1024, D_ = 1024, DS_ = 320, NSLOT_ = 512;
constexpr int H_ = 4, CH_ = 5, DFF_ = 4096;
constexpr int HD_ = D_ / H_;      // 256
constexpr int CHD_ = DS_ / CH_;   // 64
constexpr int BS_ = B_ * S_;      // 2048
constexpr int BNS_ = B_ * NSLOT_; // 1024

// ---------------- GEMM NN: C = A(MxK) @ B(KxN) (+bias) (+gelu) ----------------
// strided-batch over blockIdx.z; tiles 64x64, K-step 16, 256 thr, 4x4 micro
__global__ __launch_bounds__(256)
void k_gemm_nn(const float* __restrict__ A, int lda, long long sA,
               const float* __restrict__ Bp, int ldb, long long sB,
               float* __restrict__ C, int ldc, long long sC,
               int K, const float* __restrict__ bias, int act)
{
  A  += (long long)blockIdx.z * sA;
  Bp += (long long)blockIdx.z * sB;
  C  += (long long)blockIdx.z * sC;
  const int bm = blockIdx.y * 64;
  const int bn = blockIdx.x * 64;
  __shared__ float As[16][65];
  __shared__ float Bs[16][64];
  const int tid = threadIdx.x;
  const int tx = tid & 15, ty = tid >> 4;
  float acc[4][4] = {};
  for (int k0 = 0; k0 < K; k0 += 16) {
    {
      const int kk = tid & 15, r0 = tid >> 4;
      #pragma unroll
      for (int r = 0; r < 4; ++r)
        As[kk][r0 + r * 16] = A[(long long)(bm + r0 + r * 16) * lda + (k0 + kk)];
      const int c = tid & 63, kb = tid >> 6;
      #pragma unroll
      for (int r = 0; r < 4; ++r)
        Bs[kb + r * 4][c] = Bp[(long long)(k0 + kb + r * 4) * ldb + (bn + c)];
    }
    __syncthreads();
    #pragma unroll
    for (int kk = 0; kk < 16; ++kk) {
      float a[4], b[4];
      #pragma unroll
      for (int i = 0; i < 4; ++i) a[i] = As[kk][ty * 4 + i];
      #pragma unroll
      for (int j = 0; j < 4; ++j) b[j] = Bs[kk][tx * 4 + j];
      #pragma unroll
      for (int i = 0; i < 4; ++i)
        #pragma unroll
        for (int j = 0; j < 4; ++j)
          acc[i][j] = fmaf(a[i], b[j], acc[i][j]);
    }
    __syncthreads();
  }
  #pragma unroll
  for (int i = 0; i < 4; ++i) {
    const int row = bm + ty * 4 + i;
    #pragma unroll
    for (int j = 0; j < 4; ++j) {
      const int col = bn + tx * 4 + j;
      float v = acc[i][j];
      if (bias) v += bias[col];
      if (act == 1) { // tanh-approx gelu (jax.nn.gelu default)
        const float x = v;
        v = 0.5f * x * (1.0f + tanhf(0.7978845608028654f * (x + 0.044715f * x * x * x)));
      }
      C[(long long)row * ldc + col] = v;
    }
  }
}

// ---------------- GEMM NT: C[m,n] = sum_k A[m,k] * B[n,k] (scores) ----------------
__global__ __launch_bounds__(256)
void k_gemm_nt(const float* __restrict__ A, int lda, long long sA,
               const float* __restrict__ Bp, int ldb, long long sB,
               float* __restrict__ C, int ldc, long long sC, int K)
{
  A  += (long long)blockIdx.z * sA;
  Bp += (long long)blockIdx.z * sB;
  C  += (long long)blockIdx.z * sC;
  const int bm = blockIdx.y * 64;
  const int bn = blockIdx.x * 64;
  __shared__ float As[16][65];
  __shared__ float Bs[16][65];
  const int tid = threadIdx.x;
  const int tx = tid & 15, ty = tid >> 4;
  float acc[4][4] = {};
  for (int k0 = 0; k0 < K; k0 += 16) {
    {
      const int kk = tid & 15, r0 = tid >> 4;
      #pragma unroll
      for (int r = 0; r < 4; ++r) {
        As[kk][r0 + r * 16] = A[(long long)(bm + r0 + r * 16) * lda + (k0 + kk)];
        Bs[kk][r0 + r * 16] = Bp[(long long)(bn + r0 + r * 16) * ldb + (k0 + kk)];
      }
    }
    __syncthreads();
    #pragma unroll
    for (int kk = 0; kk < 16; ++kk) {
      float a[4], b[4];
      #pragma unroll
      for (int i = 0; i < 4; ++i) a[i] = As[kk][ty * 4 + i];
      #pragma unroll
      for (int j = 0; j < 4; ++j) b[j] = Bs[kk][tx * 4 + j];
      #pragma unroll
      for (int i = 0; i < 4; ++i)
        #pragma unroll
        for (int j = 0; j < 4; ++j)
          acc[i][j] = fmaf(a[i], b[j], acc[i][j]);
    }
    __syncthreads();
  }
  #pragma unroll
  for (int i = 0; i < 4; ++i) {
    const int row = bm + ty * 4 + i;
    #pragma unroll
    for (int j = 0; j < 4; ++j)
      C[(long long)row * ldc + (bn + tx * 4 + j)] = acc[i][j];
  }
}

// ---------------- row softmax (in place), x <- softmax(x*scale) ----------------
__global__ __launch_bounds__(256)
void k_softmax(float* __restrict__ x, int cols, float scale)
{
  float* p = x + (long long)blockIdx.x * cols;
  __shared__ float red[256];
  const int tid = threadIdx.x;
  float m = -1e30f;
  for (int c = tid; c < cols; c += 256) m = fmaxf(m, p[c] * scale);
  red[tid] = m; __syncthreads();
  for (int s = 128; s > 0; s >>= 1) { if (tid < s) red[tid] = fmaxf(red[tid], red[tid + s]); __syncthreads(); }
  m = red[0]; __syncthreads();
  float sum = 0.f;
  for (int c = tid; c < cols; c += 256) { float e = expf(p[c] * scale - m); p[c] = e; sum += e; }
  red[tid] = sum; __syncthreads();
  for (int s = 128; s > 0; s >>= 1) { if (tid < s) red[tid] += red[tid + s]; __syncthreads(); }
  const float inv = 1.0f / red[0];
  for (int c = tid; c < cols; c += 256) p[c] *= inv;
}

// ---------------- layernorm: out = LN(x + res)*g + b  (res may be null) ----------------
__global__ __launch_bounds__(256)
void k_layernorm(const float* __restrict__ x, const float* __restrict__ res,
                 const float* __restrict__ g, const float* __restrict__ b,
                 float* __restrict__ out, int cols)
{
  const long long ro = (long long)blockIdx.x * cols;
  const float* px = x + ro;
  const float* pr = res ? res + ro : nullptr;
  float* po = out + ro;
  __shared__ float red[256];
  const int tid = threadIdx.x;
  float s = 0.f;
  for (int c = tid; c < cols; c += 256) { float v = px[c] + (pr ? pr[c] : 0.f); s += v; }
  red[tid] = s; __syncthreads();
  for (int t = 128; t > 0; t >>= 1) { if (tid < t) red[tid] += red[tid + t]; __syncthreads(); }
  const float mean = red[0] / cols; __syncthreads();
  float s2 = 0.f;
  for (int c = tid; c < cols; c += 256) { float v = px[c] + (pr ? pr[c] : 0.f) - mean; s2 += v * v; }
  red[tid] = s2; __syncthreads();
  for (int t = 128; t > 0; t >>= 1) { if (tid < t) red[tid] += red[tid + t]; __syncthreads(); }
  const float inv = rsqrtf(red[0] / cols + 1e-5f);
  for (int c = tid; c < cols; c += 256) {
    float v = px[c] + (pr ? pr[c] : 0.f);
    po[c] = (v - mean) * inv * g[c] + b[c];
  }
}

// ---------------- gate[row] = sigmoid(dot(x[row,:], w) + b0)  (1 wave / row) ----------------
__global__ __launch_bounds__(256)
void k_gate(const float* __restrict__ x, const float* __restrict__ w,
            const float* __restrict__ b0, float* __restrict__ out, int cols)
{
  const int lane = threadIdx.x & 63;
  const int wv = threadIdx.x >> 6;
  const long long row = (long long)blockIdx.x * 4 + wv;
  const float* p = x + row * cols;
  float s = 0.f;
  for (int c = lane; c < cols; c += 64) s += p[c] * w[c];
  #pragma unroll
  for (int off = 32; off > 0; off >>= 1) s += __shfl_down(s, off);
  if (lane == 0) out[row] = 1.0f / (1.0f + expf(-(s + b0[0])));
}

// ---------------- elementwise helpers ----------------
// out = sa*a + (b?b:0) + emb[col]
__global__ __launch_bounds__(256)
void k_combine(float* __restrict__ out, const float* __restrict__ a, float sa,
               const float* __restrict__ b, const float* __restrict__ emb, int n, int Dm1)
{
  int i = blockIdx.x * 256 + threadIdx.x;
  if (i >= n) return;
  float v = sa * a[i];
  if (b) v += b[i];
  v += emb[i & Dm1];
  out[i] = v;
}

// out = h + gate[i/D]*r
__global__ __launch_bounds__(256)
void k_gated_add(float* __restrict__ out, const float* __restrict__ h,
                 const float* __restrict__ r, const float* __restrict__ gate, int n, int Dv)
{
  int i = blockIdx.x * 256 + threadIdx.x;
  if (i >= n) return;
  out[i] = h[i] + gate[i / Dv] * r[i];
}

// x *= gate[i/C]   (in place)
__global__ __launch_bounds__(256)
void k_scale_rows(float* __restrict__ x, const float* __restrict__ gate, int n, int Cv)
{
  int i = blockIdx.x * 256 + threadIdx.x;
  if (i >= n) return;
  x[i] *= gate[i / Cv];
}

// out = a + b
__global__ __launch_bounds__(256)
void k_add(float* __restrict__ out, const float* __restrict__ a, const float* __restrict__ b, int n)
{
  int i = blockIdx.x * 256 + threadIdx.x;
  if (i >= n) return;
  out[i] = a[i] + b[i];
}

// ---------------- host orchestration ----------------
extern "C" void kernel_launch(void* const* d_in, const int* in_sizes, int n_in,
                              void* d_out, int out_size, void* d_ws, size_t ws_size,
                              hipStream_t stream)
{
  (void)in_sizes; (void)n_in; (void)out_size;
  const float* x        = (const float*)d_in[0];
  const float* cache0   = (const float*)d_in[1];
  const float* iter_emb = (const float*)d_in[2];
  const float* rq_w     = (const float*)d_in[3];
  const float* rg_w     = (const float*)d_in[4];
  const float* rg_b     = (const float*)d_in[5];
  const float* ck_w     = (const float*)d_in[6];
  const float* cv_w     = (const float*)d_in[7];
  const float* aq_w     = (const float*)d_in[8];
  const float* ak_w     = (const float*)d_in[9];
  const float* av_w     = (const float*)d_in[10];
  const float* ao_w     = (const float*)d_in[11];
  const float* aq_b     = (const float*)d_in[12];
  const float* ak_b     = (const float*)d_in[13];
  const float* av_b     = (const float*)d_in[14];
  const float* ao_b     = (const float*)d_in[15];
  const float* f1_w     = (const float*)d_in[16];
  const float* f1_b     = (const float*)d_in[17];
  const float* f2_w     = (const float*)d_in[18];
  const float* f2_b     = (const float*)d_in[19];
  const float* n1_g     = (const float*)d_in[20];
  const float* n1_b     = (const float*)d_in[21];
  const float* n2_g     = (const float*)d_in[22];
  const float* n2_b     = (const float*)d_in[23];
  const float* sq_w     = (const float*)d_in[24];
  const float* tk_w     = (const float*)d_in[25];
  const float* tv_w     = (const float*)d_in[26];
  const float* wg_w     = (const float*)d_in[27];
  const float* wg_b     = (const float*)d_in[28];
  const float* cq_w     = (const float*)d_in[29];
  const float* ck2_w    = (const float*)d_in[30];
  const float* cv2_w    = (const float*)d_in[31];
  const float* co_w     = (const float*)d_in[32];
  const float* cq_b     = (const float*)d_in[33];
  const float* ck2_b    = (const float*)d_in[34];
  const float* cv2_b    = (const float*)d_in[35];
  const float* co_b     = (const float*)d_in[36];
  const float* cn_g     = (const float*)d_in[37];
  const float* cn_b     = (const float*)d_in[38];
  // d_in[39] = max_iterations (device scalar, fixed at 2 by setup_inputs);
  // the launch schedule must be capture-deterministic, so it is hardcoded.

  float* out = (float*)d_out;

  // -------- workspace layout (floats) --------
  size_t off = 0;
  float* wsf = (float*)d_ws;
  auto alloc = [&](size_t n) { float* p = wsf + off; off += n; return p; };
  float* hbuf  = alloc((size_t)BS_ * D_);   // iteration input h
  float* henh  = alloc((size_t)BS_ * D_);   // mem_read output
  float* hcomp = alloc((size_t)BS_ * D_);   // compute_block output (it 0)
  float* h2b   = alloc((size_t)BS_ * D_);   // post-attn LN
  float* t0    = alloc((size_t)BS_ * D_);   // hn / attnv / ff2
  float* t1    = alloc((size_t)BS_ * D_);   // qa / attno
  float* t2    = alloc((size_t)BS_ * D_);   // ka / readout
  float* scores= alloc((size_t)B_ * H_ * S_ * S_);  // 8M floats (max score buf)
  float* ffmid = alloc((size_t)BS_ * DFF_);         // 8M floats
  float* kb    = alloc((size_t)BNS_ * D_);
  float* vb    = alloc((size_t)BNS_ * D_);
  float* gate  = alloc((size_t)BS_);
  float* ccw   = alloc((size_t)BNS_ * DS_);
  float* sqb   = alloc((size_t)BNS_ * DS_);
  float* tkb   = alloc((size_t)BS_ * DS_);
  float* tvb   = alloc((size_t)BS_ * DS_);
  float* cqb   = alloc((size_t)BNS_ * DS_);
  float* ckb   = alloc((size_t)BNS_ * DS_);
  float* cvb   = alloc((size_t)BNS_ * DS_);
  if (ws_size < off * sizeof(float)) return; // workspace too small (fails loudly via absmax)

  auto gemm_nn = [&](const float* A, int lda, long long sA,
                     const float* Bp, int ldb, long long sB,
                     float* C, int ldc, long long sC,
                     int M, int N, int K, int batch,
                     const float* bias, int act) {
    dim3 g(N / 64, M / 64, batch);
    k_gemm_nn<<<g, 256, 0, stream>>>(A, lda, sA, Bp, ldb, sB, C, ldc, sC, K, bias, act);
  };
  auto gemm_nt = [&](const float* A, int lda, long long sA,
                     const float* Bp, int ldb, long long sB,
                     float* C, int ldc, long long sC,
                     int M, int N, int K, int batch) {
    dim3 g(N / 64, M / 64, batch);
    k_gemm_nt<<<g, 256, 0, stream>>>(A, lda, sA, Bp, ldb, sB, C, ldc, sC, K);
  };
  auto softmax = [&](float* p, int rows, int cols, float scale) {
    k_softmax<<<rows, 256, 0, stream>>>(p, cols, scale);
  };
  auto lnorm = [&](const float* xp, const float* rp, const float* g, const float* b,
                   float* o, int rows, int cols) {
    k_layernorm<<<rows, 256, 0, stream>>>(xp, rp, g, b, o, cols);
  };
  auto eg = [](int n) { return dim3((n + 255) / 256); };

  // -------- mem_read: henh = h + sigmoid(h@rg_w+rg_b) * attn(h@rq_w, cc@ck_w, cc@cv_w) --------
  auto mem_read = [&](const float* h, const float* ccp, float* out_henh) {
    gemm_nn(h, D_, 0, rq_w, D_, 0, t0, D_, 0, BS_, D_, D_, 1, nullptr, 0);            // q
    gemm_nn(ccp, DS_, 0, ck_w, D_, 0, kb, D_, 0, BNS_, D_, DS_, 1, nullptr, 0);       // k
    gemm_nn(ccp, DS_, 0, cv_w, D_, 0, vb, D_, 0, BNS_, D_, DS_, 1, nullptr, 0);       // v
    gemm_nt(t0, D_, (long long)S_ * D_, kb, D_, (long long)NSLOT_ * D_,
            scores, NSLOT_, (long long)S_ * NSLOT_, S_, NSLOT_, D_, B_);              // q.kT
    softmax(scores, B_ * S_, NSLOT_, 0.03125f);                                       // 1/sqrt(1024)
    gemm_nn(scores, NSLOT_, (long long)S_ * NSLOT_, vb, D_, (long long)NSLOT_ * D_,
            t2, D_, (long long)S_ * D_, S_, D_, NSLOT_, B_, nullptr, 0);              // readout
    k_gate<<<BS_ / 4, 256, 0, stream>>>(h, rg_w, rg_b, gate, D_);
    k_gated_add<<<eg(BS_ * D_), 256, 0, stream>>>(out_henh, h, t2, gate, BS_ * D_, D_);
  };

  // -------- compute_block --------
  auto compute_block = [&](const float* he, float* hout) {
    lnorm(he, nullptr, n1_g, n1_b, t0, BS_, D_);                                      // hn
    gemm_nn(t0, D_, 0, aq_w, D_, 0, t1, D_, 0, BS_, D_, D_, 1, aq_b, 0);              // qa
    gemm_nn(t0, D_, 0, ak_w, D_, 0, t2, D_, 0, BS_, D_, D_, 1, ak_b, 0);              // ka
    gemm_nn(t0, D_, 0, av_w, D_, 0, hbuf, D_, 0, BS_, D_, D_, 1, av_b, 0);            // va (hbuf free)
    for (int hh = 0; hh < H_; ++hh)
      gemm_nt(t1 + hh * HD_, D_, (long long)S_ * D_, t2 + hh * HD_, D_, (long long)S_ * D_,
              scores + (long long)hh * S_ * S_, S_, (long long)H_ * S_ * S_, S_, S_, HD_, B_);
    softmax(scores, B_ * H_ * S_, S_, 0.0625f);                                       // 1/sqrt(256)
    for (int hh = 0; hh < H_; ++hh)
      gemm_nn(scores + (long long)hh * S_ * S_, S_, (long long)H_ * S_ * S_,
              hbuf + hh * HD_, D_, (long long)S_ * D_,
              t0 + hh * HD_, D_, (long long)S_ * D_, S_, HD_, S_, B_, nullptr, 0);    // attnv
    gemm_nn(t0, D_, 0, ao_w, D_, 0, t1, D_, 0, BS_, D_, D_, 1, ao_b, 0);              // attno
    lnorm(he, t1, n1_g, n1_b, h2b, BS_, D_);                                          // h2 = LN(he+attn)
    gemm_nn(h2b, D_, 0, f1_w, DFF_, 0, ffmid, DFF_, 0, BS_, DFF_, D_, 1, f1_b, 1);    // gelu fused
    gemm_nn(ffmid, DFF_, 0, f2_w, D_, 0, t0, D_, 0, BS_, D_, DFF_, 1, f2_b, 0);       // ff2
    lnorm(h2b, t0, n2_g, n2_b, hout, BS_, D_);                                        // LN(h2+ffn)
  };

  // -------- mem_write + cache_self_attn (cc update; skipped in last iteration) --------
  auto mem_write_csa = [&](const float* hc, const float* ccin, float* ccout) {
    gemm_nn(ccin, DS_, 0, sq_w, DS_, 0, sqb, DS_, 0, BNS_, DS_, DS_, 1, nullptr, 0);
    gemm_nn(hc, D_, 0, tk_w, DS_, 0, tkb, DS_, 0, BS_, DS_, D_, 1, nullptr, 0);
    gemm_nn(hc, D_, 0, tv_w, DS_, 0, tvb, DS_, 0, BS_, DS_, D_, 1, nullptr, 0);
    k_gate<<<BS_ / 4, 256, 0, stream>>>(hc, wg_w, wg_b, gate, D_);
    k_scale_rows<<<eg(BS_ * DS_), 256, 0, stream>>>(tvb, gate, BS_ * DS_, DS_);
    gemm_nt(sqb, DS_, (long long)NSLOT_ * DS_, tkb, DS_, (long long)S_ * DS_,
            scores, S_, (long long)NSLOT_ * S_, NSLOT_, S_, DS_, B_);
    softmax(scores, B_ * NSLOT_, S_, 0.05590169943749474f);                           // 1/sqrt(320)
    gemm_nn(scores, S_, (long long)NSLOT_ * S_, tvb, DS_, (long long)S_ * DS_,
            sqb, DS_, (long long)NSLOT_ * DS_, NSLOT_, DS_, S_, B_, nullptr, 0);      // upd -> sqb
    k_add<<<eg(BNS_ * DS_), 256, 0, stream>>>(ccout, ccin, sqb, BNS_ * DS_);
    // cache self-attention on ccout
    gemm_nn(ccout, DS_, 0, cq_w, DS_, 0, cqb, DS_, 0, BNS_, DS_, DS_, 1, cq_b, 0);
    gemm_nn(ccout, DS_, 0, ck2_w, DS_, 0, ckb, DS_, 0, BNS_, DS_, DS_, 1, ck2_b, 0);
    gemm_nn(ccout, DS_, 0, cv2_w, DS_, 0, cvb, DS_, 0, BNS_, DS_, DS_, 1, cv2_b, 0);
    for (int ch = 0; ch < CH_; ++ch)
      gemm_nt(cqb + ch * CHD_, DS_, (long long)NSLOT_ * DS_, ckb + ch * CHD_, DS_, (long long)NSLOT_ * DS_,
              scores + (long long)ch * NSLOT_ * NSLOT_, NSLOT_, (long long)CH_ * NSLOT_ * NSLOT_,
              NSLOT_, NSLOT_, CHD_, B_);
    softmax(scores, B_ * CH_ * NSLOT_, NSLOT_, 0.125f);                               // 1/sqrt(64)
    for (int ch = 0; ch < CH_; ++ch)
      gemm_nn(scores + (long long)ch * NSLOT_ * NSLOT_, NSLOT_, (long long)CH_ * NSLOT_ * NSLOT_,
              cvb + ch * CHD_, DS_, (long long)NSLOT_ * DS_,
              cqb + ch * CHD_, DS_, (long long)NSLOT_ * DS_, NSLOT_, CHD_, NSLOT_, B_, nullptr, 0);
    gemm_nn(cqb, DS_, 0, co_w, DS_, 0, ckb, DS_, 0, BNS_, DS_, DS_, 1, co_b, 0);      // attn out
    lnorm(ccout, ckb, cn_g, cn_b, ccout, BNS_, DS_);                                  // cc = LN(cc+attn)
  };

  // ================= iteration 0 =================
  k_combine<<<eg(BS_ * D_), 256, 0, stream>>>(hbuf, x, 1.0f, nullptr, iter_emb, BS_ * D_, D_ - 1);
  mem_read(hbuf, cache0, henh);
  compute_block(henh, hcomp);
  mem_write_csa(hcomp, cache0, ccw);

  // ================= iteration 1 (last: cc update is dead code, skipped) =================
  // h = hcomp + iter_emb[1] + x + h_prev(=hcomp) = 2*hcomp + x + emb1
  k_combine<<<eg(BS_ * D_), 256, 0, stream>>>(hbuf, hcomp, 2.0f, x, iter_emb + D_, BS_ * D_, D_ - 1);
  mem_read(hbuf, ccw, henh);
  compute_block(henh, out);
}

// Round 2
// 1154.725 us; speedup vs baseline: 3.8630x; 3.8630x over previous
//
#include <hip/hip_runtime.h>
#include <cstdint>

// ---------------- problem constants ----------------
constexpr int B_ = 2, S_ = 1024, D_ = 1024, DS_ = 320, NSLOT_ = 512;
constexpr int H_ = 4, CH_ = 5, DFF_ = 4096;
constexpr int HD_ = D_ / H_;      // 256
constexpr int CHD_ = DS_ / CH_;   // 64
constexpr int BS_ = B_ * S_;      // 2048
constexpr int BNS_ = B_ * NSLOT_; // 1024

typedef unsigned short u16;
typedef __attribute__((ext_vector_type(8))) short bf16x8;
typedef __attribute__((ext_vector_type(4))) float f32x4;
typedef __attribute__((ext_vector_type(4))) u16 u16x4;

__device__ __forceinline__ u16 f2bf(float f) {
  unsigned u = __float_as_uint(f);
  return (u16)((u + 0x7FFFu + ((u >> 16) & 1u)) >> 16);  // RNE
}
__device__ __forceinline__ float bf2f(u16 h) { return __uint_as_float((unsigned)h << 16); }

__device__ __forceinline__ void gload16(const void* g, void* l) {
  __builtin_amdgcn_global_load_lds((const __attribute__((address_space(1))) void*)g,
                                   (__attribute__((address_space(3))) void*)l, 16, 0, 0);
}

// ---------------- bf16 MFMA GEMM: C[m,n] = sum_k A[m,k]*B[n,k] ----------------
// BM=128 fixed. BN=128 (waves 2x2) or BN=64 (waves 4x1). BK=32.
// z decomposition: zb=z/zdiv, zr=z%zdiv; operand offset = zb*s + zr*s2.
// Epilogue: +bias[n], *rowscale[m], gelu; outputs: fp32 C, bf16 C, bf16 C^T.
template<int BN, int WM, int WN>
__global__ __launch_bounds__(256)
void k_gemm(const u16* __restrict__ A, int lda, long long sA, long long sA2,
            const u16* __restrict__ Bp, int ldb, long long sB, long long sB2,
            float* __restrict__ outF, u16* __restrict__ outB,
            int ldc, long long sC, long long sC2,
            u16* __restrict__ outBT, int ldt, long long sT, long long sT2,
            int K, int zdiv, const float* __restrict__ bias,
            const float* __restrict__ rowscale, int act)
{
  constexpr int BM = 128;
  constexpr int MI = BM / (WM * 16);
  constexpr int NI = BN / (WN * 16);
  const int z = blockIdx.z, zb = z / zdiv, zr = z - zb * zdiv;
  A  += (long long)zb * sA + (long long)zr * sA2;
  Bp += (long long)zb * sB + (long long)zr * sB2;
  const long long cof = (long long)zb * sC + (long long)zr * sC2;
  const long long tof = (long long)zb * sT + (long long)zr * sT2;
  const int bm = blockIdx.y * BM, bn = blockIdx.x * BN;
  __shared__ __align__(16) u16 As[BM * 32];
  __shared__ __align__(16) u16 Bs[BN * 32];
  const int tid = threadIdx.x;
  const int lane = tid & 63, wid = tid >> 6;
  const int wm = wid / WN, wn = wid - wm * WN;
  const int rowb = wm * (BM / WM), colb = wn * (BN / WN);

  f32x4 acc[MI][NI];
  const f32x4 fz = {0.f, 0.f, 0.f, 0.f};
  #pragma unroll
  for (int i = 0; i < MI; ++i)
    #pragma unroll
    for (int j = 0; j < NI; ++j) acc[i][j] = fz;

  // staging: thread t covers row (t>>2), 8 bf16 at elem (t&3)*8 of a 64-row group
  const u16* gA = A + (long long)(bm + (tid >> 2)) * lda + (tid & 3) * 8;
  const u16* gB = Bp + (long long)(bn + (tid >> 2)) * ldb + (tid & 3) * 8;
  char* lA = (char*)As + wid * 1024;
  char* lB = (char*)Bs + wid * 1024;
  const u16* fa = As + ((rowb + (lane & 15)) * 32 + (lane >> 4) * 8);
  const u16* fb = Bs + ((colb + (lane & 15)) * 32 + (lane >> 4) * 8);

  for (int k0 = 0; k0 < K; k0 += 32) {
    gload16(gA + k0, lA);
    gload16(gA + (long long)64 * lda + k0, lA + 4096);
    gload16(gB + k0, lB);
    if constexpr (BN == 128) gload16(gB + (long long)64 * ldb + k0, lB + 4096);
    __syncthreads();
    bf16x8 af[MI], bv[NI];
    #pragma unroll
    for (int i = 0; i < MI; ++i) af[i] = *(const bf16x8*)(fa + i * 16 * 32);
    #pragma unroll
    for (int j = 0; j < NI; ++j) bv[j] = *(const bf16x8*)(fb + j * 16 * 32);
    #pragma unroll
    for (int i = 0; i < MI; ++i)
      #pragma unroll
      for (int j = 0; j < NI; ++j)
        acc[i][j] = __builtin_amdgcn_mfma_f32_16x16x32_bf16(af[i], bv[j], acc[i][j], 0, 0, 0);
    __syncthreads();
  }

  const int fr = lane & 15, fq = lane >> 4;
  #pragma unroll
  for (int i = 0; i < MI; ++i) {
    const int r0 = bm + rowb + i * 16 + fq * 4;
    #pragma unroll
    for (int j = 0; j < NI; ++j) {
      const int cn = bn + colb + j * 16 + fr;
      const float bvv = bias ? bias[cn] : 0.f;
      float vv[4];
      #pragma unroll
      for (int t = 0; t < 4; ++t) {
        float v = acc[i][j][t] + bvv;
        if (rowscale) v *= rowscale[r0 + t];
        if (act) v = 0.5f * v * (1.f + tanhf(0.7978845608028654f * (v + 0.044715f * v * v * v)));
        vv[t] = v;
      }
      if (outF) {
        #pragma unroll
        for (int t = 0; t < 4; ++t) outF[cof + (long long)(r0 + t) * ldc + cn] = vv[t];
      }
      if (outB) {
        #pragma unroll
        for (int t = 0; t < 4; ++t) outB[cof + (long long)(r0 + t) * ldc + cn] = f2bf(vv[t]);
      }
      if (outBT) {
        u16x4 pk = {f2bf(vv[0]), f2bf(vv[1]), f2bf(vv[2]), f2bf(vv[3])};
        *(u16x4*)(outBT + tof + (long long)cn * ldt + r0) = pk;
      }
    }
  }
}

// ---------------- transpose + convert: in[R][C] fp32 -> out[C][R] bf16 ----------------
__global__ __launch_bounds__(256)
void k_tcvt(const float* __restrict__ in, u16* __restrict__ out, int R, int C)
{
  __shared__ float t[32][33];
  const int bx = blockIdx.x * 32, by = blockIdx.y * 32;
  const int tx = threadIdx.x & 31, ty = threadIdx.x >> 5;
  #pragma unroll
  for (int i = 0; i < 32; i += 8)
    t[ty + i][tx] = in[(long long)(by + ty + i) * C + bx + tx];
  __syncthreads();
  #pragma unroll
  for (int i = 0; i < 32; i += 8)
    out[(long long)(bx + ty + i) * R + by + tx] = f2bf(t[tx][ty + i]);
}

// ---------------- convert fp32 -> bf16 ----------------
__global__ __launch_bounds__(256)
void k_cvt(const float* __restrict__ in, u16* __restrict__ out, int n)
{
  int i = blockIdx.x * 256 + threadIdx.x;
  if (i < n) out[i] = f2bf(in[i]);
}

// ---------------- row softmax on bf16 in place (cols <= 1024) ----------------
__global__ __launch_bounds__(256)
void k_softmax_b16(u16* __restrict__ x, int cols, float scale)
{
  u16* p = x + (long long)blockIdx.x * cols;
  const int tid = threadIdx.x;
  __shared__ float red[256];
  float v[4];
  float m = -1e30f;
  #pragma unroll
  for (int i = 0; i < 4; ++i) {
    const int c = tid + (i << 8);
    v[i] = (c < cols) ? bf2f(p[c]) * scale : -1e30f;
    m = fmaxf(m, v[i]);
  }
  red[tid] = m; __syncthreads();
  for (int s = 128; s > 0; s >>= 1) { if (tid < s) red[tid] = fmaxf(red[tid], red[tid + s]); __syncthreads(); }
  m = red[0]; __syncthreads();
  float sum = 0.f;
  #pragma unroll
  for (int i = 0; i < 4; ++i) { v[i] = expf(v[i] - m); sum += v[i]; }
  red[tid] = sum; __syncthreads();
  for (int s = 128; s > 0; s >>= 1) { if (tid < s) red[tid] += red[tid + s]; __syncthreads(); }
  const float inv = 1.f / red[0];
  #pragma unroll
  for (int i = 0; i < 4; ++i) {
    const int c = tid + (i << 8);
    if (c < cols) p[c] = f2bf(v[i] * inv);
  }
}

// ---------------- layernorm: LN(x [+res])*g + b -> fp32 out (opt) + bf16 out (opt) ----------------
__global__ __launch_bounds__(256)
void k_layernorm(const float* __restrict__ x, const float* __restrict__ res,
                 const float* __restrict__ g, const float* __restrict__ b,
                 float* __restrict__ outF, u16* __restrict__ outB, int cols)
{
  const long long ro = (long long)blockIdx.x * cols;
  const float* px = x + ro;
  const float* pr = res ? res + ro : nullptr;
  __shared__ float red[256];
  const int tid = threadIdx.x;
  float s = 0.f;
  for (int c = tid; c < cols; c += 256) { float v = px[c] + (pr ? pr[c] : 0.f); s += v; }
  red[tid] = s; __syncthreads();
  for (int t = 128; t > 0; t >>= 1) { if (tid < t) red[tid] += red[tid + t]; __syncthreads(); }
  const float mean = red[0] / cols; __syncthreads();
  float s2 = 0.f;
  for (int c = tid; c < cols; c += 256) { float v = px[c] + (pr ? pr[c] : 0.f) - mean; s2 += v * v; }
  red[tid] = s2; __syncthreads();
  for (int t = 128; t > 0; t >>= 1) { if (tid < t) red[tid] += red[tid + t]; __syncthreads(); }
  const float inv = rsqrtf(red[0] / cols + 1e-5f);
  for (int c = tid; c < cols; c += 256) {
    float v = (px[c] + (pr ? pr[c] : 0.f) - mean) * inv * g[c] + b[c];
    if (outF) outF[ro + c] = v;
    if (outB) outB[ro + c] = f2bf(v);
  }
}

// ---------------- gate[row] = sigmoid(dot(x[row], w) + b0), 1 wave / row ----------------
__global__ __launch_bounds__(256)
void k_gate(const float* __restrict__ x, const float* __restrict__ w,
            const float* __restrict__ b0, float* __restrict__ out, int cols)
{
  const int lane = threadIdx.x & 63;
  const int wv = threadIdx.x >> 6;
  const long long row = (long long)blockIdx.x * 4 + wv;
  const float* p = x + row * cols;
  float s = 0.f;
  for (int c = lane; c < cols; c += 64) s += p[c] * w[c];
  #pragma unroll
  for (int off = 32; off > 0; off >>= 1) s += __shfl_down(s, off);
  if (lane == 0) out[row] = 1.0f / (1.0f + expf(-(s + b0[0])));
}

// ---------------- elementwise ----------------
// out = sa*a + (b?b:0) + emb[col]; dual output
__global__ __launch_bounds__(256)
void k_combine2(float* __restrict__ oF, u16* __restrict__ oB,
                const float* __restrict__ a, float sa, const float* __restrict__ b,
                const float* __restrict__ emb, int n, int Dm1)
{
  int i = blockIdx.x * 256 + threadIdx.x;
  if (i >= n) return;
  float v = sa * a[i];
  if (b) v += b[i];
  v += emb[i & Dm1];
  oF[i] = v; oB[i] = f2bf(v);
}

// out = h + gate[i/D]*r  (fp32)
__global__ __launch_bounds__(256)
void k_gated_add(float* __restrict__ out, const float* __restrict__ h,
                 const float* __restrict__ r, const float* __restrict__ gate, int n, int Dv)
{
  int i = blockIdx.x * 256 + threadIdx.x;
  if (i >= n) return;
  out[i] = h[i] + gate[i / Dv] * r[i];
}

// dual add
__global__ __launch_bounds__(256)
void k_add2(float* __restrict__ oF, u16* __restrict__ oB,
            const float* __restrict__ a, const float* __restrict__ b, int n)
{
  int i = blockIdx.x * 256 + threadIdx.x;
  if (i >= n) return;
  float v = a[i] + b[i];
  oF[i] = v; oB[i] = f2bf(v);
}

// ---------------- host ----------------
extern "C" void kernel_launch(void* const* d_in, const int* in_sizes, int n_in,
                              void* d_out, int out_size, void* d_ws, size_t ws_size,
                              hipStream_t stream)
{
  (void)in_sizes; (void)n_in; (void)out_size;
  const float* x        = (const float*)d_in[0];
  const float* cache0   = (const float*)d_in[1];
  const float* iter_emb = (const float*)d_in[2];
  const float* rq_w     = (const float*)d_in[3];
  const float* rg_w     = (const float*)d_in[4];
  const float* rg_b     = (const float*)d_in[5];
  const float* ck_w     = (const float*)d_in[6];
  const float* cv_w     = (const float*)d_in[7];
  const float* aq_w     = (const float*)d_in[8];
  const float* ak_w     = (const float*)d_in[9];
  const float* av_w     = (const float*)d_in[10];
  const float* ao_w     = (const float*)d_in[11];
  const float* aq_b     = (const float*)d_in[12];
  const float* ak_b     = (const float*)d_in[13];
  const float* av_b     = (const float*)d_in[14];
  const float* ao_b     = (const float*)d_in[15];
  const float* f1_w     = (const float*)d_in[16];
  const float* f1_b     = (const float*)d_in[17];
  const float* f2_w     = (const float*)d_in[18];
  const float* f2_b     = (const float*)d_in[19];
  const float* n1_g     = (const float*)d_in[20];
  const float* n1_b     = (const float*)d_in[21];
  const float* n2_g     = (const float*)d_in[22];
  const float* n2_b     = (const float*)d_in[23];
  const float* sq_w     = (const float*)d_in[24];
  const float* tk_w     = (const float*)d_in[25];
  const float* tv_w     = (const float*)d_in[26];
  const float* wg_w     = (const float*)d_in[27];
  const float* wg_b     = (const float*)d_in[28];
  const float* cq_w     = (const float*)d_in[29];
  const float* ck2_w    = (const float*)d_in[30];
  const float* cv2_w    = (const float*)d_in[31];
  const float* co_w     = (const float*)d_in[32];
  const float* cq_b     = (const float*)d_in[33];
  const float* ck2_b    = (const float*)d_in[34];
  const float* cv2_b    = (const float*)d_in[35];
  const float* co_b     = (const float*)d_in[36];
  const float* cn_g     = (const float*)d_in[37];
  const float* cn_b     = (const float*)d_in[38];
  // d_in[39] = max_iterations (fixed 2; schedule hardcoded for graph capture)

  float* out = (float*)d_out;

  // -------- workspace carve --------
  size_t off = 0;
  char* base = (char*)d_ws;
  auto allocF = [&](size_t n) { float* p = (float*)(base + off); off += n * 4; off = (off + 255) & ~(size_t)255; return p; };
  auto allocH = [&](size_t n) { u16* p = (u16*)(base + off); off += n * 2; off = (off + 255) & ~(size_t)255; return p; };

  // fp32
  float* hbuf  = allocF((size_t)BS_ * D_);
  float* henh  = allocF((size_t)BS_ * D_);
  float* hcomp = allocF((size_t)BS_ * D_);
  float* h2b   = allocF((size_t)BS_ * D_);
  float* tA    = allocF((size_t)BS_ * D_);   // readout / attno / f2out
  float* gate  = allocF((size_t)BS_);
  float* ccnf  = allocF((size_t)BNS_ * DS_);
  float* updf  = allocF((size_t)BNS_ * DS_);
  float* coo   = allocF((size_t)BNS_ * DS_);
  float* ccwf  = allocF((size_t)BNS_ * DS_);
  // bf16 weights (transposed [N][K])
  u16* rqT  = allocH((size_t)D_ * D_);
  u16* ckT  = allocH((size_t)D_ * DS_);
  u16* cvT  = allocH((size_t)D_ * DS_);
  u16* aqT  = allocH((size_t)D_ * D_);
  u16* akT  = allocH((size_t)D_ * D_);
  u16* avT  = allocH((size_t)D_ * D_);
  u16* aoT  = allocH((size_t)D_ * D_);
  u16* f1T  = allocH((size_t)DFF_ * D_);
  u16* f2T  = allocH((size_t)D_ * DFF_);
  u16* sqT  = allocH((size_t)DS_ * DS_);
  u16* tkT  = allocH((size_t)DS_ * D_);
  u16* tvTw = allocH((size_t)DS_ * D_);
  u16* cqT  = allocH((size_t)DS_ * DS_);
  u16* ck2T = allocH((size_t)DS_ * DS_);
  u16* cv2T = allocH((size_t)DS_ * DS_);
  u16* coT  = allocH((size_t)DS_ * DS_);
  // bf16 activations
  u16* bb1  = allocH((size_t)BS_ * D_);     // h / hn / h2b
  u16* bb2  = allocH((size_t)BS_ * D_);     // q / qa / attnv-out
  u16* bb3  = allocH((size_t)BS_ * D_);     // k / ka / hcomp
  u16* bb4  = allocH((size_t)BS_ * D_);     // vT / vaT
  u16* bb5  = allocH((size_t)B_ * H_ * S_ * S_); // scores/probs / ffmid
  u16* cc0b = allocH((size_t)BNS_ * DS_);
  u16* ccwb = allocH((size_t)BNS_ * DS_);
  u16* sqb  = allocH((size_t)BNS_ * DS_);
  u16* tkb  = allocH((size_t)BS_ * DS_);
  u16* tvTb = allocH((size_t)DS_ * BS_);
  u16* ccnb = allocH((size_t)BNS_ * DS_);
  u16* cqb  = allocH((size_t)BNS_ * DS_);
  u16* ck2b = allocH((size_t)BNS_ * DS_);
  u16* cv2Tb= allocH((size_t)DS_ * BNS_);
  u16* csab = allocH((size_t)BNS_ * DS_);
  if (off > ws_size) return;

  auto gemm = [&](int M, int N, int K, int z, int zdiv,
                  const u16* Ap, int lda, long long sa, long long sa2,
                  const u16* Bq, int ldb, long long sb, long long sb2,
                  float* oF, u16* oB, int ldc, long long sc, long long sc2,
                  u16* oBT, int ldt, long long st, long long st2,
                  const float* bias, const float* rsc, int act) {
    if (N % 128 == 0) {
      dim3 g(N / 128, M / 128, z);
      k_gemm<128, 2, 2><<<g, 256, 0, stream>>>(Ap, lda, sa, sa2, Bq, ldb, sb, sb2,
          oF, oB, ldc, sc, sc2, oBT, ldt, st, st2, K, zdiv, bias, rsc, act);
    } else {
      dim3 g(N / 64, M / 128, z);
      k_gemm<64, 4, 1><<<g, 256, 0, stream>>>(Ap, lda, sa, sa2, Bq, ldb, sb, sb2,
          oF, oB, ldc, sc, sc2, oBT, ldt, st, st2, K, zdiv, bias, rsc, act);
    }
  };
  auto tcvt = [&](const float* in, u16* o, int R, int C) {
    dim3 g(C / 32, R / 32);
    k_tcvt<<<g, 256, 0, stream>>>(in, o, R, C);
  };
  auto lnorm = [&](const float* xp, const float* rp, const float* g, const float* b,
                   float* oF, u16* oB, int rows, int cols) {
    k_layernorm<<<rows, 256, 0, stream>>>(xp, rp, g, b, oF, oB, cols);
  };
  auto eg = [](int n) { return dim3((n + 255) / 256); };

  // ---- weight prep (once per launch) ----
  tcvt(rq_w, rqT, D_, D_);
  tcvt(ck_w, ckT, DS_, D_);
  tcvt(cv_w, cvT, DS_, D_);
  tcvt(aq_w, aqT, D_, D_);
  tcvt(ak_w, akT, D_, D_);
  tcvt(av_w, avT, D_, D_);
  tcvt(ao_w, aoT, D_, D_);
  tcvt(f1_w, f1T, D_, DFF_);
  tcvt(f2_w, f2T, DFF_, D_);
  tcvt(sq_w, sqT, DS_, DS_);
  tcvt(tk_w, tkT, D_, DS_);
  tcvt(tv_w, tvTw, D_, DS_);
  tcvt(cq_w, cqT, DS_, DS_);
  tcvt(ck2_w, ck2T, DS_, DS_);
  tcvt(cv2_w, cv2T, DS_, DS_);
  tcvt(co_w, coT, DS_, DS_);
  k_cvt<<<eg(BNS_ * DS_), 256, 0, stream>>>(cache0, cc0b, BNS_ * DS_);

  // ---- mem_read: henh = h + sigmoid(h@rg)*attn(h@rq, cc@ck, cc@cv) ----
  auto mem_read = [&](const float* h_f, const u16* h_b, const u16* cc_b, float* o_henh) {
    gemm(BS_, D_, D_, 1, 1, h_b, D_, 0, 0, rqT, D_, 0, 0,
         nullptr, bb2, D_, 0, 0, nullptr, 0, 0, 0, nullptr, nullptr, 0);            // q
    gemm(BNS_, D_, DS_, 1, 1, cc_b, DS_, 0, 0, ckT, DS_, 0, 0,
         nullptr, bb3, D_, 0, 0, nullptr, 0, 0, 0, nullptr, nullptr, 0);            // k
    gemm(BNS_, D_, DS_, 1, 1, cc_b, DS_, 0, 0, cvT, DS_, 0, 0,
         nullptr, nullptr, 0, 0, 0, bb4, BNS_, 0, 0, nullptr, nullptr, 0);          // v^T
    gemm(S_, NSLOT_, D_, B_, 1, bb2, D_, (long long)S_ * D_, 0,
         bb3, D_, (long long)NSLOT_ * D_, 0,
         nullptr, bb5, NSLOT_, (long long)S_ * NSLOT_, 0,
         nullptr, 0, 0, 0, nullptr, nullptr, 0);                                    // q k^T
    k_softmax_b16<<<B_ * S_, 256, 0, stream>>>(bb5, NSLOT_, 0.03125f);
    gemm(S_, D_, NSLOT_, B_, 1, bb5, NSLOT_, (long long)S_ * NSLOT_, 0,
         bb4, BNS_, NSLOT_, 0,
         tA, nullptr, D_, (long long)S_ * D_, 0,
         nullptr, 0, 0, 0, nullptr, nullptr, 0);                                    // readout
    k_gate<<<BS_ / 4, 256, 0, stream>>>(h_f, rg_w, rg_b, gate, D_);
    k_gated_add<<<eg(BS_ * D_), 256, 0, stream>>>(o_henh, h_f, tA, gate, BS_ * D_, D_);
  };

  // ---- compute_block ----
  auto compute_block = [&](const float* he, float* oF, u16* oB) {
    lnorm(he, nullptr, n1_g, n1_b, nullptr, bb1, BS_, D_);                          // hn (bf16 only)
    gemm(BS_, D_, D_, 1, 1, bb1, D_, 0, 0, aqT, D_, 0, 0,
         nullptr, bb2, D_, 0, 0, nullptr, 0, 0, 0, aq_b, nullptr, 0);               // qa
    gemm(BS_, D_, D_, 1, 1, bb1, D_, 0, 0, akT, D_, 0, 0,
         nullptr, bb3, D_, 0, 0, nullptr, 0, 0, 0, ak_b, nullptr, 0);               // ka
    gemm(BS_, D_, D_, 1, 1, bb1, D_, 0, 0, avT, D_, 0, 0,
         nullptr, nullptr, 0, 0, 0, bb4, BS_, 0, 0, av_b, nullptr, 0);              // va^T
    gemm(S_, S_, HD_, B_ * H_, H_,
         bb2, D_, (long long)S_ * D_, HD_,
         bb3, D_, (long long)S_ * D_, HD_,
         nullptr, bb5, S_, (long long)H_ * S_ * S_, (long long)S_ * S_,
         nullptr, 0, 0, 0, nullptr, nullptr, 0);                                    // scores
    k_softmax_b16<<<B_ * H_ * S_, 256, 0, stream>>>(bb5, S_, 0.0625f);
    gemm(S_, HD_, S_, B_ * H_, H_,
         bb5, S_, (long long)H_ * S_ * S_, (long long)S_ * S_,
         bb4, BS_, S_, (long long)HD_ * BS_,
         nullptr, bb2, D_, (long long)S_ * D_, HD_,
         nullptr, 0, 0, 0, nullptr, nullptr, 0);                                    // attnv
    gemm(BS_, D_, D_, 1, 1, bb2, D_, 0, 0, aoT, D_, 0, 0,
         tA, nullptr, D_, 0, 0, nullptr, 0, 0, 0, ao_b, nullptr, 0);                // attno
    lnorm(he, tA, n1_g, n1_b, h2b, bb1, BS_, D_);                                   // h2
    gemm(BS_, DFF_, D_, 1, 1, bb1, D_, 0, 0, f1T, D_, 0, 0,
         nullptr, bb5, DFF_, 0, 0, nullptr, 0, 0, 0, f1_b, nullptr, 1);             // f1+gelu
    gemm(BS_, D_, DFF_, 1, 1, bb5, DFF_, 0, 0, f2T, DFF_, 0, 0,
         tA, nullptr, D_, 0, 0, nullptr, 0, 0, 0, f2_b, nullptr, 0);                // f2
    lnorm(h2b, tA, n2_g, n2_b, oF, oB, BS_, D_);                                    // out
  };

  // ---- mem_write + cache self-attn (skipped in last iter) ----
  auto mem_write_csa = [&](const float* hc_f, const u16* hc_b,
                           const float* ccin_f, const u16* ccin_b) {
    gemm(BNS_, DS_, DS_, 1, 1, ccin_b, DS_, 0, 0, sqT, DS_, 0, 0,
         nullptr, sqb, DS_, 0, 0, nullptr, 0, 0, 0, nullptr, nullptr, 0);           // sq
    gemm(BS_, DS_, D_, 1, 1, hc_b, D_, 0, 0, tkT, D_, 0, 0,
         nullptr, tkb, DS_, 0, 0, nullptr, 0, 0, 0, nullptr, nullptr, 0);           // tk
    k_gate<<<BS_ / 4, 256, 0, stream>>>(hc_f, wg_w, wg_b, gate, D_);
    gemm(BS_, DS_, D_, 1, 1, hc_b, D_, 0, 0, tvTw, D_, 0, 0,
         nullptr, nullptr, 0, 0, 0, tvTb, BS_, 0, 0, nullptr, gate, 0);             // (gate*tv)^T
    gemm(NSLOT_, S_, DS_, B_, 1, sqb, DS_, (long long)NSLOT_ * DS_, 0,
         tkb, DS_, (long long)S_ * DS_, 0,
         nullptr, bb5, S_, (long long)NSLOT_ * S_, 0,
         nullptr, 0, 0, 0, nullptr, nullptr, 0);                                    // slot scores
    k_softmax_b16<<<B_ * NSLOT_, 256, 0, stream>>>(bb5, S_, 0.05590169943749474f);
    gemm(NSLOT_, DS_, S_, B_, 1, bb5, S_, (long long)NSLOT_ * S_, 0,
         tvTb, BS_, S_, 0,
         updf, nullptr, DS_, (long long)NSLOT_ * DS_, 0,
         nullptr, 0, 0, 0, nullptr, nullptr, 0);                                    // upd
    k_add2<<<eg(BNS_ * DS_), 256, 0, stream>>>(ccnf, ccnb, ccin_f, updf, BNS_ * DS_);
    gemm(BNS_, DS_, DS_, 1, 1, ccnb, DS_, 0, 0, cqT, DS_, 0, 0,
         nullptr, cqb, DS_, 0, 0, nullptr, 0, 0, 0, cq_b, nullptr, 0);              // cq
    gemm(BNS_, DS_, DS_, 1, 1, ccnb, DS_, 0, 0, ck2T, DS_, 0, 0,
         nullptr, ck2b, DS_, 0, 0, nullptr, 0, 0, 0, ck2_b, nullptr, 0);            // ck
    gemm(BNS_, DS_, DS_, 1, 1, ccnb, DS_, 0, 0, cv2T, DS_, 0, 0,
         nullptr, nullptr, 0, 0, 0, cv2Tb, BNS_, 0, 0, cv2_b, nullptr, 0);          // cv^T
    gemm(NSLOT_, NSLOT_, CHD_, B_ * CH_, CH_,
         cqb, DS_, (long long)NSLOT_ * DS_, CHD_,
         ck2b, DS_, (long long)NSLOT_ * DS_, CHD_,
         nullptr, bb5, NSLOT_, (long long)CH_ * NSLOT_ * NSLOT_, (long long)NSLOT_ * NSLOT_,
         nullptr, 0, 0, 0, nullptr, nullptr, 0);                                    // csa scores
    k_softmax_b16<<<B_ * CH_ * NSLOT_, 256, 0, stream>>>(bb5, NSLOT_, 0.125f);
    gemm(NSLOT_, CHD_, NSLOT_, B_ * CH_, CH_,
         bb5, NSLOT_, (long long)CH_ * NSLOT_ * NSLOT_, (long long)NSLOT_ * NSLOT_,
         cv2Tb, BNS_, NSLOT_, (long long)CHD_ * BNS_,
         nullptr, csab, DS_, (long long)NSLOT_ * DS_, CHD_,
         nullptr, 0, 0, 0, nullptr, nullptr, 0);                                    // csa pv
    gemm(BNS_, DS_, DS_, 1, 1, csab, DS_, 0, 0, coT, DS_, 0, 0,
         coo, nullptr, DS_, 0, 0, nullptr, 0, 0, 0, co_b, nullptr, 0);              // co
    lnorm(ccnf, coo, cn_g, cn_b, ccwf, ccwb, BNS_, DS_);                            // cc out
  };

  // ================= iteration 0 =================
  k_combine2<<<eg(BS_ * D_), 256, 0, stream>>>(hbuf, bb1, x, 1.0f, nullptr, iter_emb, BS_ * D_, D_ - 1);
  mem_read(hbuf, bb1, cc0b, henh);
  compute_block(henh, hcomp, bb3);
  mem_write_csa(hcomp, bb3, cache0, cc0b);

  // ================= iteration 1 (last: cache update dead, skipped) =================
  k_combine2<<<eg(BS_ * D_), 256, 0, stream>>>(hbuf, bb1, hcomp, 2.0f, x, iter_emb + D_, BS_ * D_, D_ - 1);
  mem_read(hbuf, bb1, ccwb, henh);
  compute_block(henh, out, nullptr);
}

// Round 3
// 815.882 us; speedup vs baseline: 5.4674x; 1.4153x over previous
//
#include <hip/hip_runtime.h>
#include <cstdint>

// ---------------- problem constants ----------------
constexpr int B_ = 2, S_ = 1024, D_ = 1024, DS_ = 320, NSLOT_ = 512;
constexpr int H_ = 4, CH_ = 5, DFF_ = 4096;
constexpr int HD_ = D_ / H_;      // 256
constexpr int CHD_ = DS_ / CH_;   // 64
constexpr int BS_ = B_ * S_;      // 2048
constexpr int BNS_ = B_ * NSLOT_; // 1024

typedef unsigned short u16;
typedef __attribute__((ext_vector_type(8))) short bf16x8;
typedef __attribute__((ext_vector_type(4))) float f32x4;
typedef __attribute__((ext_vector_type(4))) u16 u16x4;

__device__ __forceinline__ u16 f2bf(float f) {
  unsigned u = __float_as_uint(f);
  return (u16)((u + 0x7FFFu + ((u >> 16) & 1u)) >> 16);  // RNE
}
__device__ __forceinline__ float bf2f(u16 h) { return __uint_as_float((unsigned)h << 16); }

__device__ __forceinline__ void gload16(const void* g, void* l) {
  __builtin_amdgcn_global_load_lds((const __attribute__((address_space(1))) void*)g,
                                   (__attribute__((address_space(3))) void*)l, 16, 0, 0);
}

// ---------------- bf16 MFMA GEMM: C[m,n] = sum_k A[m,k]*B[n,k] ----------------
// BM=128. BN=128 (waves 2x2) or BN=64 (waves 4x1). BK=32.
// 2-phase double-buffered pipeline + XOR-swizzled LDS (linear dest, pre-swizzled
// global source granule; same involution on the fragment read) -> conflict-free.
// z decomposition: zb=z/zdiv, zr=z%zdiv; operand offset = zb*s + zr*s2.
// Epilogue: +bias[n], *rowscale[m], gelu; outputs: fp32 C, bf16 C, bf16 C^T.
template<int BN, int WM, int WN>
__global__ __launch_bounds__(256)
void k_gemm(const u16* __restrict__ A, int lda, long long sA, long long sA2,
            const u16* __restrict__ Bp, int ldb, long long sB, long long sB2,
            float* __restrict__ outF, u16* __restrict__ outB,
            int ldc, long long sC, long long sC2,
            u16* __restrict__ outBT, int ldt, long long sT, long long sT2,
            int K, int zdiv, const float* __restrict__ bias,
            const float* __restrict__ rowscale, int act)
{
  constexpr int BM = 128;
  constexpr int MI = BM / (WM * 16);
  constexpr int NI = BN / (WN * 16);
  constexpr int ABYT = BM * 64;            // bytes per A K-tile (BK=32 bf16 = 64B/row)
  constexpr int BBYT = BN * 64;
  constexpr int BUF = ABYT + BBYT;
  const int z = blockIdx.z, zb = z / zdiv, zr = z - zb * zdiv;
  A  += (long long)zb * sA + (long long)zr * sA2;
  Bp += (long long)zb * sB + (long long)zr * sB2;
  const long long cof = (long long)zb * sC + (long long)zr * sC2;
  const long long tof = (long long)zb * sT + (long long)zr * sT2;
  const int bm = blockIdx.y * BM, bn = blockIdx.x * BN;
  __shared__ __align__(16) char lds[2 * BUF];
  const int tid = threadIdx.x;
  const int lane = tid & 63, wid = tid >> 6;
  const int wm = wid / WN, wn = wid - wm * WN;
  const int rowb = wm * (BM / WM), colb = wn * (BN / WN);

  f32x4 acc[MI][NI];
  const f32x4 fz = {0.f, 0.f, 0.f, 0.f};
  #pragma unroll
  for (int i = 0; i < MI; ++i)
    #pragma unroll
    for (int j = 0; j < NI; ++j) acc[i][j] = fz;

  // staging: thread t -> row t>>2, LDS granule p=t&3 (linear dest = lane*16);
  // source granule = p ^ ((row>>1)&3) = p ^ ((t>>3)&3)
  const int srow = tid >> 2;
  const int sgr  = (tid & 3) ^ ((tid >> 3) & 3);
  const u16* gA = A + (long long)(bm + srow) * lda + sgr * 8;
  const u16* gB = Bp + (long long)(bn + srow) * ldb + sgr * 8;

  // fragment read: row r' = base + (lane&15), logical granule q=lane>>4 at
  // swizzled position q ^ ((r>>1)&3)
  const int r = lane & 15, q = lane >> 4;
  const int sa_off = (rowb + r) * 64 + ((q ^ ((r >> 1) & 3)) << 4);
  const int sb_off = (colb + r) * 64 + ((q ^ ((r >> 1) & 3)) << 4);

  auto stage = [&](int buf, int k0) {
    char* la = lds + buf * BUF + wid * 1024;
    char* lb = lds + buf * BUF + ABYT + wid * 1024;
    gload16(gA + k0, la);
    gload16(gA + (long long)64 * lda + k0, la + 4096);
    gload16(gB + k0, lb);
    if constexpr (BN == 128) gload16(gB + (long long)64 * ldb + k0, lb + 4096);
  };

  stage(0, 0);
  __syncthreads();
  int cur = 0;
  for (int k0 = 0; k0 < K; k0 += 32) {
    const int nxt = cur ^ 1;
    if (k0 + 32 < K) stage(nxt, k0 + 32);
    const char* pa = lds + cur * BUF + sa_off;
    const char* pb = lds + cur * BUF + ABYT + sb_off;
    bf16x8 af[MI], bv[NI];
    #pragma unroll
    for (int i = 0; i < MI; ++i) af[i] = *(const bf16x8*)(pa + i * 1024);
    #pragma unroll
    for (int j = 0; j < NI; ++j) bv[j] = *(const bf16x8*)(pb + j * 1024);
    #pragma unroll
    for (int i = 0; i < MI; ++i)
      #pragma unroll
      for (int j = 0; j < NI; ++j)
        acc[i][j] = __builtin_amdgcn_mfma_f32_16x16x32_bf16(af[i], bv[j], acc[i][j], 0, 0, 0);
    __syncthreads();   // drains prefetch vmcnt + ds reads; next iter overwrites cur
    cur = nxt;
  }

  const int fr = lane & 15, fq = lane >> 4;
  #pragma unroll
  for (int i = 0; i < MI; ++i) {
    const int r0 = bm + rowb + i * 16 + fq * 4;
    #pragma unroll
    for (int j = 0; j < NI; ++j) {
      const int cn = bn + colb + j * 16 + fr;
      const float bvv = bias ? bias[cn] : 0.f;
      float vv[4];
      #pragma unroll
      for (int t = 0; t < 4; ++t) {
        float v = acc[i][j][t] + bvv;
        if (rowscale) v *= rowscale[r0 + t];
        if (act) v = 0.5f * v * (1.f + tanhf(0.7978845608028654f * (v + 0.044715f * v * v * v)));
        vv[t] = v;
      }
      if (outF) {
        #pragma unroll
        for (int t = 0; t < 4; ++t) outF[cof + (long long)(r0 + t) * ldc + cn] = vv[t];
      }
      if (outB) {
        #pragma unroll
        for (int t = 0; t < 4; ++t) outB[cof + (long long)(r0 + t) * ldc + cn] = f2bf(vv[t]);
      }
      if (outBT) {
        u16x4 pk = {f2bf(vv[0]), f2bf(vv[1]), f2bf(vv[2]), f2bf(vv[3])};
        *(u16x4*)(outBT + tof + (long long)cn * ldt + r0) = pk;
      }
    }
  }
}

// ---------------- transpose + convert: in[R][C] fp32 -> out[C][R] bf16 ----------------
__global__ __launch_bounds__(256)
void k_tcvt(const float* __restrict__ in, u16* __restrict__ out, int R, int C)
{
  __shared__ float t[32][33];
  const int bx = blockIdx.x * 32, by = blockIdx.y * 32;
  const int tx = threadIdx.x & 31, ty = threadIdx.x >> 5;
  #pragma unroll
  for (int i = 0; i < 32; i += 8)
    t[ty + i][tx] = in[(long long)(by + ty + i) * C + bx + tx];
  __syncthreads();
  #pragma unroll
  for (int i = 0; i < 32; i += 8)
    out[(long long)(bx + ty + i) * R + by + tx] = f2bf(t[tx][ty + i]);
}

// ---------------- convert fp32 -> bf16 ----------------
__global__ __launch_bounds__(256)
void k_cvt(const float* __restrict__ in, u16* __restrict__ out, int n)
{
  int i = blockIdx.x * 256 + threadIdx.x;
  if (i < n) out[i] = f2bf(in[i]);
}

// ---------------- row softmax on bf16 in place (cols <= 1024) ----------------
__global__ __launch_bounds__(256)
void k_softmax_b16(u16* __restrict__ x, int cols, float scale)
{
  u16* p = x + (long long)blockIdx.x * cols;
  const int tid = threadIdx.x;
  __shared__ float red[256];
  float v[4];
  float m = -1e30f;
  #pragma unroll
  for (int i = 0; i < 4; ++i) {
    const int c = tid + (i << 8);
    v[i] = (c < cols) ? bf2f(p[c]) * scale : -1e30f;
    m = fmaxf(m, v[i]);
  }
  red[tid] = m; __syncthreads();
  for (int s = 128; s > 0; s >>= 1) { if (tid < s) red[tid] = fmaxf(red[tid], red[tid + s]); __syncthreads(); }
  m = red[0]; __syncthreads();
  float sum = 0.f;
  #pragma unroll
  for (int i = 0; i < 4; ++i) { v[i] = expf(v[i] - m); sum += v[i]; }
  red[tid] = sum; __syncthreads();
  for (int s = 128; s > 0; s >>= 1) { if (tid < s) red[tid] += red[tid + s]; __syncthreads(); }
  const float inv = 1.f / red[0];
  #pragma unroll
  for (int i = 0; i < 4; ++i) {
    const int c = tid + (i << 8);
    if (c < cols) p[c] = f2bf(v[i] * inv);
  }
}

// ---------------- layernorm: LN(x [+res])*g + b -> fp32 out (opt) + bf16 out (opt) ----------------
__global__ __launch_bounds__(256)
void k_layernorm(const float* __restrict__ x, const float* __restrict__ res,
                 const float* __restrict__ g, const float* __restrict__ b,
                 float* __restrict__ outF, u16* __restrict__ outB, int cols)
{
  const long long ro = (long long)blockIdx.x * cols;
  const float* px = x + ro;
  const float* pr = res ? res + ro : nullptr;
  __shared__ float red[256];
  const int tid = threadIdx.x;
  float s = 0.f;
  for (int c = tid; c < cols; c += 256) { float v = px[c] + (pr ? pr[c] : 0.f); s += v; }
  red[tid] = s; __syncthreads();
  for (int t = 128; t > 0; t >>= 1) { if (tid < t) red[tid] += red[tid + t]; __syncthreads(); }
  const float mean = red[0] / cols; __syncthreads();
  float s2 = 0.f;
  for (int c = tid; c < cols; c += 256) { float v = px[c] + (pr ? pr[c] : 0.f) - mean; s2 += v * v; }
  red[tid] = s2; __syncthreads();
  for (int t = 128; t > 0; t >>= 1) { if (tid < t) red[tid] += red[tid + t]; __syncthreads(); }
  const float inv = rsqrtf(red[0] / cols + 1e-5f);
  for (int c = tid; c < cols; c += 256) {
    float v = (px[c] + (pr ? pr[c] : 0.f) - mean) * inv * g[c] + b[c];
    if (outF) outF[ro + c] = v;
    if (outB) outB[ro + c] = f2bf(v);
  }
}

// ---------------- gate[row] = sigmoid(dot(x[row], w) + b0), 1 wave / row ----------------
__global__ __launch_bounds__(256)
void k_gate(const float* __restrict__ x, const float* __restrict__ w,
            const float* __restrict__ b0, float* __restrict__ out, int cols)
{
  const int lane = threadIdx.x & 63;
  const int wv = threadIdx.x >> 6;
  const long long row = (long long)blockIdx.x * 4 + wv;
  const float* p = x + row * cols;
  float s = 0.f;
  for (int c = lane; c < cols; c += 64) s += p[c] * w[c];
  #pragma unroll
  for (int off = 32; off > 0; off >>= 1) s += __shfl_down(s, off);
  if (lane == 0) out[row] = 1.0f / (1.0f + expf(-(s + b0[0])));
}

// ---------------- elementwise ----------------
__global__ __launch_bounds__(256)
void k_combine2(float* __restrict__ oF, u16* __restrict__ oB,
                const float* __restrict__ a, float sa, const float* __restrict__ b,
                const float* __restrict__ emb, int n, int Dm1)
{
  int i = blockIdx.x * 256 + threadIdx.x;
  if (i >= n) return;
  float v = sa * a[i];
  if (b) v += b[i];
  v += emb[i & Dm1];
  oF[i] = v; oB[i] = f2bf(v);
}

__global__ __launch_bounds__(256)
void k_gated_add(float* __restrict__ out, const float* __restrict__ h,
                 const float* __restrict__ r, const float* __restrict__ gate, int n, int Dv)
{
  int i = blockIdx.x * 256 + threadIdx.x;
  if (i >= n) return;
  out[i] = h[i] + gate[i / Dv] * r[i];
}

__global__ __launch_bounds__(256)
void k_add2(float* __restrict__ oF, u16* __restrict__ oB,
            const float* __restrict__ a, const float* __restrict__ b, int n)
{
  int i = blockIdx.x * 256 + threadIdx.x;
  if (i >= n) return;
  float v = a[i] + b[i];
  oF[i] = v; oB[i] = f2bf(v);
}

// ---------------- host ----------------
extern "C" void kernel_launch(void* const* d_in, const int* in_sizes, int n_in,
                              void* d_out, int out_size, void* d_ws, size_t ws_size,
                              hipStream_t stream)
{
  (void)in_sizes; (void)n_in; (void)out_size;
  const float* x        = (const float*)d_in[0];
  const float* cache0   = (const float*)d_in[1];
  const float* iter_emb = (const float*)d_in[2];
  const float* rq_w     = (const float*)d_in[3];
  const float* rg_w     = (const float*)d_in[4];
  const float* rg_b     = (const float*)d_in[5];
  const float* ck_w     = (const float*)d_in[6];
  const float* cv_w     = (const float*)d_in[7];
  const float* aq_w     = (const float*)d_in[8];
  const float* ak_w     = (const float*)d_in[9];
  const float* av_w     = (const float*)d_in[10];
  const float* ao_w     = (const float*)d_in[11];
  const float* aq_b     = (const float*)d_in[12];
  const float* ak_b     = (const float*)d_in[13];
  const float* av_b     = (const float*)d_in[14];
  const float* ao_b     = (const float*)d_in[15];
  const float* f1_w     = (const float*)d_in[16];
  const float* f1_b     = (const float*)d_in[17];
  const float* f2_w     = (const float*)d_in[18];
  const float* f2_b     = (const float*)d_in[19];
  const float* n1_g     = (const float*)d_in[20];
  const float* n1_b     = (const float*)d_in[21];
  const float* n2_g     = (const float*)d_in[22];
  const float* n2_b     = (const float*)d_in[23];
  const float* sq_w     = (const float*)d_in[24];
  const float* tk_w     = (const float*)d_in[25];
  const float* tv_w     = (const float*)d_in[26];
  const float* wg_w     = (const float*)d_in[27];
  const float* wg_b     = (const float*)d_in[28];
  const float* cq_w     = (const float*)d_in[29];
  const float* ck2_w    = (const float*)d_in[30];
  const float* cv2_w    = (const float*)d_in[31];
  const float* co_w     = (const float*)d_in[32];
  const float* cq_b     = (const float*)d_in[33];
  const float* ck2_b    = (const float*)d_in[34];
  const float* cv2_b    = (const float*)d_in[35];
  const float* co_b     = (const float*)d_in[36];
  const float* cn_g     = (const float*)d_in[37];
  const float* cn_b     = (const float*)d_in[38];
  // d_in[39] = max_iterations (fixed 2; schedule hardcoded for graph capture)

  float* out = (float*)d_out;

  // -------- workspace carve --------
  size_t off = 0;
  char* base = (char*)d_ws;
  auto allocF = [&](size_t n) { float* p = (float*)(base + off); off += n * 4; off = (off + 255) & ~(size_t)255; return p; };
  auto allocH = [&](size_t n) { u16* p = (u16*)(base + off); off += n * 2; off = (off + 255) & ~(size_t)255; return p; };

  float* hbuf  = allocF((size_t)BS_ * D_);
  float* henh  = allocF((size_t)BS_ * D_);
  float* hcomp = allocF((size_t)BS_ * D_);
  float* h2b   = allocF((size_t)BS_ * D_);
  float* tA    = allocF((size_t)BS_ * D_);
  float* gate  = allocF((size_t)BS_);
  float* ccnf  = allocF((size_t)BNS_ * DS_);
  float* updf  = allocF((size_t)BNS_ * DS_);
  float* coo   = allocF((size_t)BNS_ * DS_);
  float* ccwf  = allocF((size_t)BNS_ * DS_);
  u16* rqT  = allocH((size_t)D_ * D_);
  u16* ckT  = allocH((size_t)D_ * DS_);
  u16* cvT  = allocH((size_t)D_ * DS_);
  u16* aqT  = allocH((size_t)D_ * D_);
  u16* akT  = allocH((size_t)D_ * D_);
  u16* avT  = allocH((size_t)D_ * D_);
  u16* aoT  = allocH((size_t)D_ * D_);
  u16* f1T  = allocH((size_t)DFF_ * D_);
  u16* f2T  = allocH((size_t)D_ * DFF_);
  u16* sqT  = allocH((size_t)DS_ * DS_);
  u16* tkT  = allocH((size_t)DS_ * D_);
  u16* tvTw = allocH((size_t)DS_ * D_);
  u16* cqT  = allocH((size_t)DS_ * DS_);
  u16* ck2T = allocH((size_t)DS_ * DS_);
  u16* cv2T = allocH((size_t)DS_ * DS_);
  u16* coT  = allocH((size_t)DS_ * DS_);
  u16* bb1  = allocH((size_t)BS_ * D_);
  u16* bb2  = allocH((size_t)BS_ * D_);
  u16* bb3  = allocH((size_t)BS_ * D_);
  u16* bb4  = allocH((size_t)BS_ * D_);
  u16* bb5  = allocH((size_t)B_ * H_ * S_ * S_);
  u16* cc0b = allocH((size_t)BNS_ * DS_);
  u16* ccwb = allocH((size_t)BNS_ * DS_);
  u16* sqb  = allocH((size_t)BNS_ * DS_);
  u16* tkb  = allocH((size_t)BS_ * DS_);
  u16* tvTb = allocH((size_t)DS_ * BS_);
  u16* ccnb = allocH((size_t)BNS_ * DS_);
  u16* cqb  = allocH((size_t)BNS_ * DS_);
  u16* ck2b = allocH((size_t)BNS_ * DS_);
  u16* cv2Tb= allocH((size_t)DS_ * BNS_);
  u16* csab = allocH((size_t)BNS_ * DS_);
  if (off > ws_size) return;

  auto gemm = [&](int M, int N, int K, int z, int zdiv,
                  const u16* Ap, int lda, long long sa, long long sa2,
                  const u16* Bq, int ldb, long long sb, long long sb2,
                  float* oF, u16* oB, int ldc, long long sc, long long sc2,
                  u16* oBT, int ldt, long long st, long long st2,
                  const float* bias, const float* rsc, int act) {
    const long long blocks128 = (N % 128 == 0) ? (long long)(N / 128) * (M / 128) * z : 0;
    if (N % 128 == 0 && blocks128 >= 192) {
      dim3 g(N / 128, M / 128, z);
      k_gemm<128, 2, 2><<<g, 256, 0, stream>>>(Ap, lda, sa, sa2, Bq, ldb, sb, sb2,
          oF, oB, ldc, sc, sc2, oBT, ldt, st, st2, K, zdiv, bias, rsc, act);
    } else {
      dim3 g(N / 64, M / 128, z);
      k_gemm<64, 4, 1><<<g, 256, 0, stream>>>(Ap, lda, sa, sa2, Bq, ldb, sb, sb2,
          oF, oB, ldc, sc, sc2, oBT, ldt, st, st2, K, zdiv, bias, rsc, act);
    }
  };
  auto tcvt = [&](const float* in, u16* o, int R, int C) {
    dim3 g(C / 32, R / 32);
    k_tcvt<<<g, 256, 0, stream>>>(in, o, R, C);
  };
  auto lnorm = [&](const float* xp, const float* rp, const float* g, const float* b,
                   float* oF, u16* oB, int rows, int cols) {
    k_layernorm<<<rows, 256, 0, stream>>>(xp, rp, g, b, oF, oB, cols);
  };
  auto eg = [](int n) { return dim3((n + 255) / 256); };

  // ---- weight prep ----
  tcvt(rq_w, rqT, D_, D_);
  tcvt(ck_w, ckT, DS_, D_);
  tcvt(cv_w, cvT, DS_, D_);
  tcvt(aq_w, aqT, D_, D_);
  tcvt(ak_w, akT, D_, D_);
  tcvt(av_w, avT, D_, D_);
  tcvt(ao_w, aoT, D_, D_);
  tcvt(f1_w, f1T, D_, DFF_);
  tcvt(f2_w, f2T, DFF_, D_);
  tcvt(sq_w, sqT, DS_, DS_);
  tcvt(tk_w, tkT, D_, DS_);
  tcvt(tv_w, tvTw, D_, DS_);
  tcvt(cq_w, cqT, DS_, DS_);
  tcvt(ck2_w, ck2T, DS_, DS_);
  tcvt(cv2_w, cv2T, DS_, DS_);
  tcvt(co_w, coT, DS_, DS_);
  k_cvt<<<eg(BNS_ * DS_), 256, 0, stream>>>(cache0, cc0b, BNS_ * DS_);

  // ---- mem_read ----
  auto mem_read = [&](const float* h_f, const u16* h_b, const u16* cc_b, float* o_henh) {
    gemm(BS_, D_, D_, 1, 1, h_b, D_, 0, 0, rqT, D_, 0, 0,
         nullptr, bb2, D_, 0, 0, nullptr, 0, 0, 0, nullptr, nullptr, 0);            // q
    gemm(BNS_, D_, DS_, 1, 1, cc_b, DS_, 0, 0, ckT, DS_, 0, 0,
         nullptr, bb3, D_, 0, 0, nullptr, 0, 0, 0, nullptr, nullptr, 0);            // k
    gemm(BNS_, D_, DS_, 1, 1, cc_b, DS_, 0, 0, cvT, DS_, 0, 0,
         nullptr, nullptr, 0, 0, 0, bb4, BNS_, 0, 0, nullptr, nullptr, 0);          // v^T
    gemm(S_, NSLOT_, D_, B_, 1, bb2, D_, (long long)S_ * D_, 0,
         bb3, D_, (long long)NSLOT_ * D_, 0,
         nullptr, bb5, NSLOT_, (long long)S_ * NSLOT_, 0,
         nullptr, 0, 0, 0, nullptr, nullptr, 0);                                    // q k^T
    k_softmax_b16<<<B_ * S_, 256, 0, stream>>>(bb5, NSLOT_, 0.03125f);
    gemm(S_, D_, NSLOT_, B_, 1, bb5, NSLOT_, (long long)S_ * NSLOT_, 0,
         bb4, BNS_, NSLOT_, 0,
         tA, nullptr, D_, (long long)S_ * D_, 0,
         nullptr, 0, 0, 0, nullptr, nullptr, 0);                                    // readout
    k_gate<<<BS_ / 4, 256, 0, stream>>>(h_f, rg_w, rg_b, gate, D_);
    k_gated_add<<<eg(BS_ * D_), 256, 0, stream>>>(o_henh, h_f, tA, gate, BS_ * D_, D_);
  };

  // ---- compute_block ----
  auto compute_block = [&](const float* he, float* oF, u16* oB) {
    lnorm(he, nullptr, n1_g, n1_b, nullptr, bb1, BS_, D_);
    gemm(BS_, D_, D_, 1, 1, bb1, D_, 0, 0, aqT, D_, 0, 0,
         nullptr, bb2, D_, 0, 0, nullptr, 0, 0, 0, aq_b, nullptr, 0);               // qa
    gemm(BS_, D_, D_, 1, 1, bb1, D_, 0, 0, akT, D_, 0, 0,
         nullptr, bb3, D_, 0, 0, nullptr, 0, 0, 0, ak_b, nullptr, 0);               // ka
    gemm(BS_, D_, D_, 1, 1, bb1, D_, 0, 0, avT, D_, 0, 0,
         nullptr, nullptr, 0, 0, 0, bb4, BS_, 0, 0, av_b, nullptr, 0);              // va^T
    gemm(S_, S_, HD_, B_ * H_, H_,
         bb2, D_, (long long)S_ * D_, HD_,
         bb3, D_, (long long)S_ * D_, HD_,
         nullptr, bb5, S_, (long long)H_ * S_ * S_, (long long)S_ * S_,
         nullptr, 0, 0, 0, nullptr, nullptr, 0);                                    // scores
    k_softmax_b16<<<B_ * H_ * S_, 256, 0, stream>>>(bb5, S_, 0.0625f);
    gemm(S_, HD_, S_, B_ * H_, H_,
         bb5, S_, (long long)H_ * S_ * S_, (long long)S_ * S_,
         bb4, BS_, S_, (long long)HD_ * BS_,
         nullptr, bb2, D_, (long long)S_ * D_, HD_,
         nullptr, 0, 0, 0, nullptr, nullptr, 0);                                    // attnv
    gemm(BS_, D_, D_, 1, 1, bb2, D_, 0, 0, aoT, D_, 0, 0,
         tA, nullptr, D_, 0, 0, nullptr, 0, 0, 0, ao_b, nullptr, 0);                // attno
    lnorm(he, tA, n1_g, n1_b, h2b, bb1, BS_, D_);
    gemm(BS_, DFF_, D_, 1, 1, bb1, D_, 0, 0, f1T, D_, 0, 0,
         nullptr, bb5, DFF_, 0, 0, nullptr, 0, 0, 0, f1_b, nullptr, 1);             // f1+gelu
    gemm(BS_, D_, DFF_, 1, 1, bb5, DFF_, 0, 0, f2T, DFF_, 0, 0,
         tA, nullptr, D_, 0, 0, nullptr, 0, 0, 0, f2_b, nullptr, 0);                // f2
    lnorm(h2b, tA, n2_g, n2_b, oF, oB, BS_, D_);
  };

  // ---- mem_write + cache self-attn (skipped in last iter) ----
  auto mem_write_csa = [&](const float* hc_f, const u16* hc_b,
                           const float* ccin_f, const u16* ccin_b) {
    gemm(BNS_, DS_, DS_, 1, 1, ccin_b, DS_, 0, 0, sqT, DS_, 0, 0,
         nullptr, sqb, DS_, 0, 0, nullptr, 0, 0, 0, nullptr, nullptr, 0);           // sq
    gemm(BS_, DS_, D_, 1, 1, hc_b, D_, 0, 0, tkT, D_, 0, 0,
         nullptr, tkb, DS_, 0, 0, nullptr, 0, 0, 0, nullptr, nullptr, 0);           // tk
    k_gate<<<BS_ / 4, 256, 0, stream>>>(hc_f, wg_w, wg_b, gate, D_);
    gemm(BS_, DS_, D_, 1, 1, hc_b, D_, 0, 0, tvTw, D_, 0, 0,
         nullptr, nullptr, 0, 0, 0, tvTb, BS_, 0, 0, nullptr, gate, 0);             // (gate*tv)^T
    gemm(NSLOT_, S_, DS_, B_, 1, sqb, DS_, (long long)NSLOT_ * DS_, 0,
         tkb, DS_, (long long)S_ * DS_, 0,
         nullptr, bb5, S_, (long long)NSLOT_ * S_, 0,
         nullptr, 0, 0, 0, nullptr, nullptr, 0);                                    // slot scores
    k_softmax_b16<<<B_ * NSLOT_, 256, 0, stream>>>(bb5, S_, 0.05590169943749474f);
    gemm(NSLOT_, DS_, S_, B_, 1, bb5, S_, (long long)NSLOT_ * S_, 0,
         tvTb, BS_, S_, 0,
         updf, nullptr, DS_, (long long)NSLOT_ * DS_, 0,
         nullptr, 0, 0, 0, nullptr, nullptr, 0);                                    // upd
    k_add2<<<eg(BNS_ * DS_), 256, 0, stream>>>(ccnf, ccnb, ccin_f, updf, BNS_ * DS_);
    gemm(BNS_, DS_, DS_, 1, 1, ccnb, DS_, 0, 0, cqT, DS_, 0, 0,
         nullptr, cqb, DS_, 0, 0, nullptr, 0, 0, 0, cq_b, nullptr, 0);              // cq
    gemm(BNS_, DS_, DS_, 1, 1, ccnb, DS_, 0, 0, ck2T, DS_, 0, 0,
         nullptr, ck2b, DS_, 0, 0, nullptr, 0, 0, 0, ck2_b, nullptr, 0);            // ck
    gemm(BNS_, DS_, DS_, 1, 1, ccnb, DS_, 0, 0, cv2T, DS_, 0, 0,
         nullptr, nullptr, 0, 0, 0, cv2Tb, BNS_, 0, 0, cv2_b, nullptr, 0);          // cv^T
    gemm(NSLOT_, NSLOT_, CHD_, B_ * CH_, CH_,
         cqb, DS_, (long long)NSLOT_ * DS_, CHD_,
         ck2b, DS_, (long long)NSLOT_ * DS_, CHD_,
         nullptr, bb5, NSLOT_, (long long)CH_ * NSLOT_ * NSLOT_, (long long)NSLOT_ * NSLOT_,
         nullptr, 0, 0, 0, nullptr, nullptr, 0);                                    // csa scores
    k_softmax_b16<<<B_ * CH_ * NSLOT_, 256, 0, stream>>>(bb5, NSLOT_, 0.125f);
    gemm(NSLOT_, CHD_, NSLOT_, B_ * CH_, CH_,
         bb5, NSLOT_, (long long)CH_ * NSLOT_ * NSLOT_, (long long)NSLOT_ * NSLOT_,
         cv2Tb, BNS_, NSLOT_, (long long)CHD_ * BNS_,
         nullptr, csab, DS_, (long long)NSLOT_ * DS_, CHD_,
         nullptr, 0, 0, 0, nullptr, nullptr, 0);                                    // csa pv
    gemm(BNS_, DS_, DS_, 1, 1, csab, DS_, 0, 0, coT, DS_, 0, 0,
         coo, nullptr, DS_, 0, 0, nullptr, 0, 0, 0, co_b, nullptr, 0);              // co
    lnorm(ccnf, coo, cn_g, cn_b, ccwf, ccwb, BNS_, DS_);
  };

  // ================= iteration 0 =================
  k_combine2<<<eg(BS_ * D_), 256, 0, stream>>>(hbuf, bb1, x, 1.0f, nullptr, iter_emb, BS_ * D_, D_ - 1);
  mem_read(hbuf, bb1, cc0b, henh);
  compute_block(henh, hcomp, bb3);
  mem_write_csa(hcomp, bb3, cache0, cc0b);

  // ================= iteration 1 (last: cache update dead, skipped) =================
  k_combine2<<<eg(BS_ * D_), 256, 0, stream>>>(hbuf, bb1, hcomp, 2.0f, x, iter_emb + D_, BS_ * D_, D_ - 1);
  mem_read(hbuf, bb1, ccwb, henh);
  compute_block(henh, out, nullptr);
}

// Round 4
// 765.629 us; speedup vs baseline: 5.8262x; 1.0656x over previous
//
#include <hip/hip_runtime.h>
#include <cstdint>

// ---------------- problem constants ----------------
constexpr int B_ = 2, S_ = 1024, D_ = 1024, DS_ = 320, NSLOT_ = 512;
constexpr int H_ = 4, CH_ = 5, DFF_ = 4096;
constexpr int HD_ = D_ / H_;      // 256
constexpr int CHD_ = DS_ / CH_;   // 64
constexpr int BS_ = B_ * S_;      // 2048
constexpr int BNS_ = B_ * NSLOT_; // 1024

typedef unsigned short u16;
typedef __attribute__((ext_vector_type(8))) short bf16x8;
typedef __attribute__((ext_vector_type(4))) float f32x4;
typedef __attribute__((ext_vector_type(4))) u16 u16x4;

__device__ __forceinline__ u16 f2bf(float f) {
  unsigned u = __float_as_uint(f);
  return (u16)((u + 0x7FFFu + ((u >> 16) & 1u)) >> 16);  // RNE
}
__device__ __forceinline__ float bf2f(u16 h) { return __uint_as_float((unsigned)h << 16); }

__device__ __forceinline__ void gload16(const void* g, void* l) {
  __builtin_amdgcn_global_load_lds((const __attribute__((address_space(1))) void*)g,
                                   (__attribute__((address_space(3))) void*)l, 16, 0, 0);
}

// ---------------- bf16 MFMA GEMM: C[m,n] = sum_k A[m,k]*B[n,k] ----------------
// BM=128. BN=128 (waves 2x2, 4 stage-loads) or BN=64 (waves 4x1, 3 stage-loads).
// BK=32. Double-buffered with COUNTED vmcnt (T4): tile t+1's global_load_lds
// stay in flight across tile t's compute; never drain vmcnt(0) in the loop.
// XOR-swizzled LDS: linear gload_lds dest, pre-swizzled global source granule,
// same involution on the fragment read (conflict-free, verified r3: 0 conflicts).
template<int BN, int WM, int WN>
__global__ __launch_bounds__(256)
void k_gemm(const u16* __restrict__ A, int lda, long long sA, long long sA2,
            const u16* __restrict__ Bp, int ldb, long long sB, long long sB2,
            float* __restrict__ outF, u16* __restrict__ outB,
            int ldc, long long sC, long long sC2,
            u16* __restrict__ outBT, int ldt, long long sT, long long sT2,
            int K, int zdiv, const float* __restrict__ bias,
            const float* __restrict__ rowscale, int act)
{
  constexpr int BM = 128;
  constexpr int MI = BM / (WM * 16);
  constexpr int NI = BN / (WN * 16);
  constexpr int ABYT = BM * 64;            // bytes per A K-tile (BK=32 bf16 = 64B/row)
  constexpr int BBYT = BN * 64;
  constexpr int BUF = ABYT + BBYT;
  const int z = blockIdx.z, zb = z / zdiv, zr = z - zb * zdiv;
  A  += (long long)zb * sA + (long long)zr * sA2;
  Bp += (long long)zb * sB + (long long)zr * sB2;
  const long long cof = (long long)zb * sC + (long long)zr * sC2;
  const long long tof = (long long)zb * sT + (long long)zr * sT2;
  const int bm = blockIdx.y * BM, bn = blockIdx.x * BN;
  __shared__ __align__(16) char lds[2 * BUF];
  const int tid = threadIdx.x;
  const int lane = tid & 63, wid = tid >> 6;
  const int wm = wid / WN, wn = wid - wm * WN;
  const int rowb = wm * (BM / WM), colb = wn * (BN / WN);

  f32x4 acc[MI][NI];
  const f32x4 fz = {0.f, 0.f, 0.f, 0.f};
  #pragma unroll
  for (int i = 0; i < MI; ++i)
    #pragma unroll
    for (int j = 0; j < NI; ++j) acc[i][j] = fz;

  // staging: thread t -> row t>>2, LDS granule p=t&3 (linear dest = lane*16);
  // source granule = p ^ ((row>>1)&3) = p ^ ((t>>3)&3)
  const int srow = tid >> 2;
  const int sgr  = (tid & 3) ^ ((tid >> 3) & 3);
  const u16* gA = A + (long long)(bm + srow) * lda + sgr * 8;
  const u16* gB = Bp + (long long)(bn + srow) * ldb + sgr * 8;

  // fragment read: row base + (lane&15), logical granule q=lane>>4 at q ^ ((r>>1)&3)
  const int r = lane & 15, q = lane >> 4;
  const int sa_off = (rowb + r) * 64 + ((q ^ ((r >> 1) & 3)) << 4);
  const int sb_off = (colb + r) * 64 + ((q ^ ((r >> 1) & 3)) << 4);

  auto stage = [&](int buf, int k0) {
    char* la = lds + buf * BUF + wid * 1024;
    char* lb = lds + buf * BUF + ABYT + wid * 1024;
    gload16(gA + k0, la);
    gload16(gA + (long long)64 * lda + k0, la + 4096);
    gload16(gB + k0, lb);
    if constexpr (BN == 128) gload16(gB + (long long)64 * ldb + k0, lb + 4096);
  };

  stage(0, 0);
  int cur = 0;
  for (int k0 = 0; k0 < K; k0 += 32) {
    const int nxt = cur ^ 1;
    const bool hasNext = (k0 + 32 < K);
    if (hasNext) {
      stage(nxt, k0 + 32);
      if constexpr (BN == 128) asm volatile("s_waitcnt vmcnt(4)" ::: "memory");
      else                     asm volatile("s_waitcnt vmcnt(3)" ::: "memory");
    } else {
      asm volatile("s_waitcnt vmcnt(0)" ::: "memory");
    }
    __builtin_amdgcn_s_barrier();           // all waves' tile-t loads landed
    __builtin_amdgcn_sched_barrier(0);
    const char* pa = lds + cur * BUF + sa_off;
    const char* pb = lds + cur * BUF + ABYT + sb_off;
    bf16x8 af[MI], bv[NI];
    #pragma unroll
    for (int i = 0; i < MI; ++i) af[i] = *(const bf16x8*)(pa + i * 1024);
    #pragma unroll
    for (int j = 0; j < NI; ++j) bv[j] = *(const bf16x8*)(pb + j * 1024);
    #pragma unroll
    for (int i = 0; i < MI; ++i)
      #pragma unroll
      for (int j = 0; j < NI; ++j)
        acc[i][j] = __builtin_amdgcn_mfma_f32_16x16x32_bf16(af[i], bv[j], acc[i][j], 0, 0, 0);
    asm volatile("s_waitcnt lgkmcnt(0)" ::: "memory");  // ds_reads of buf[cur] done
    __builtin_amdgcn_sched_barrier(0);
    __builtin_amdgcn_s_barrier();           // safe to overwrite buf[cur] next iter
    cur = nxt;
  }

  const int fr = lane & 15, fq = lane >> 4;
  #pragma unroll
  for (int i = 0; i < MI; ++i) {
    const int r0 = bm + rowb + i * 16 + fq * 4;
    #pragma unroll
    for (int j = 0; j < NI; ++j) {
      const int cn = bn + colb + j * 16 + fr;
      const float bvv = bias ? bias[cn] : 0.f;
      float vv[4];
      #pragma unroll
      for (int t = 0; t < 4; ++t) {
        float v = acc[i][j][t] + bvv;
        if (rowscale) v *= rowscale[r0 + t];
        if (act) v = 0.5f * v * (1.f + tanhf(0.7978845608028654f * (v + 0.044715f * v * v * v)));
        vv[t] = v;
      }
      if (outF) {
        #pragma unroll
        for (int t = 0; t < 4; ++t) outF[cof + (long long)(r0 + t) * ldc + cn] = vv[t];
      }
      if (outB) {
        #pragma unroll
        for (int t = 0; t < 4; ++t) outB[cof + (long long)(r0 + t) * ldc + cn] = f2bf(vv[t]);
      }
      if (outBT) {
        u16x4 pk = {f2bf(vv[0]), f2bf(vv[1]), f2bf(vv[2]), f2bf(vv[3])};
        *(u16x4*)(outBT + tof + (long long)cn * ldt + r0) = pk;
      }
    }
  }
}

// ---------------- transpose + convert: in[R][C] fp32 -> out[C][R] bf16 ----------------
__global__ __launch_bounds__(256)
void k_tcvt(const float* __restrict__ in, u16* __restrict__ out, int R, int C)
{
  __shared__ float t[32][33];
  const int bx = blockIdx.x * 32, by = blockIdx.y * 32;
  const int tx = threadIdx.x & 31, ty = threadIdx.x >> 5;
  #pragma unroll
  for (int i = 0; i < 32; i += 8)
    t[ty + i][tx] = in[(long long)(by + ty + i) * C + bx + tx];
  __syncthreads();
  #pragma unroll
  for (int i = 0; i < 32; i += 8)
    out[(long long)(bx + ty + i) * R + by + tx] = f2bf(t[tx][ty + i]);
}

// ---------------- convert fp32 -> bf16 ----------------
__global__ __launch_bounds__(256)
void k_cvt(const float* __restrict__ in, u16* __restrict__ out, int n)
{
  int i = blockIdx.x * 256 + threadIdx.x;
  if (i < n) out[i] = f2bf(in[i]);
}

// ---------------- row softmax on bf16 in place (cols <= 1024) ----------------
__global__ __launch_bounds__(256)
void k_softmax_b16(u16* __restrict__ x, int cols, float scale)
{
  u16* p = x + (long long)blockIdx.x * cols;
  const int tid = threadIdx.x;
  __shared__ float red[256];
  float v[4];
  float m = -1e30f;
  #pragma unroll
  for (int i = 0; i < 4; ++i) {
    const int c = tid + (i << 8);
    v[i] = (c < cols) ? bf2f(p[c]) * scale : -1e30f;
    m = fmaxf(m, v[i]);
  }
  red[tid] = m; __syncthreads();
  for (int s = 128; s > 0; s >>= 1) { if (tid < s) red[tid] = fmaxf(red[tid], red[tid + s]); __syncthreads(); }
  m = red[0]; __syncthreads();
  float sum = 0.f;
  #pragma unroll
  for (int i = 0; i < 4; ++i) { v[i] = expf(v[i] - m); sum += v[i]; }
  red[tid] = sum; __syncthreads();
  for (int s = 128; s > 0; s >>= 1) { if (tid < s) red[tid] += red[tid + s]; __syncthreads(); }
  const float inv = 1.f / red[0];
  #pragma unroll
  for (int i = 0; i < 4; ++i) {
    const int c = tid + (i << 8);
    if (c < cols) p[c] = f2bf(v[i] * inv);
  }
}

// ---------------- layernorm: LN(x [+res])*g + b -> fp32 out (opt) + bf16 out (opt) ----------------
__global__ __launch_bounds__(256)
void k_layernorm(const float* __restrict__ x, const float* __restrict__ res,
                 const float* __restrict__ g, const float* __restrict__ b,
                 float* __restrict__ outF, u16* __restrict__ outB, int cols)
{
  const long long ro = (long long)blockIdx.x * cols;
  const float* px = x + ro;
  const float* pr = res ? res + ro : nullptr;
  __shared__ float red[256];
  const int tid = threadIdx.x;
  float s = 0.f;
  for (int c = tid; c < cols; c += 256) { float v = px[c] + (pr ? pr[c] : 0.f); s += v; }
  red[tid] = s; __syncthreads();
  for (int t = 128; t > 0; t >>= 1) { if (tid < t) red[tid] += red[tid + t]; __syncthreads(); }
  const float mean = red[0] / cols; __syncthreads();
  float s2 = 0.f;
  for (int c = tid; c < cols; c += 256) { float v = px[c] + (pr ? pr[c] : 0.f) - mean; s2 += v * v; }
  red[tid] = s2; __syncthreads();
  for (int t = 128; t > 0; t >>= 1) { if (tid < t) red[tid] += red[tid + t]; __syncthreads(); }
  const float inv = rsqrtf(red[0] / cols + 1e-5f);
  for (int c = tid; c < cols; c += 256) {
    float v = (px[c] + (pr ? pr[c] : 0.f) - mean) * inv * g[c] + b[c];
    if (outF) outF[ro + c] = v;
    if (outB) outB[ro + c] = f2bf(v);
  }
}

// ---------------- gate[row] = sigmoid(dot(x[row], w) + b0), 1 wave / row ----------------
__global__ __launch_bounds__(256)
void k_gate(const float* __restrict__ x, const float* __restrict__ w,
            const float* __restrict__ b0, float* __restrict__ out, int cols)
{
  const int lane = threadIdx.x & 63;
  const int wv = threadIdx.x >> 6;
  const long long row = (long long)blockIdx.x * 4 + wv;
  const float* p = x + row * cols;
  float s = 0.f;
  for (int c = lane; c < cols; c += 64) s += p[c] * w[c];
  #pragma unroll
  for (int off = 32; off > 0; off >>= 1) s += __shfl_down(s, off);
  if (lane == 0) out[row] = 1.0f / (1.0f + expf(-(s + b0[0])));
}

// ---------------- elementwise ----------------
__global__ __launch_bounds__(256)
void k_combine2(float* __restrict__ oF, u16* __restrict__ oB,
                const float* __restrict__ a, float sa, const float* __restrict__ b,
                const float* __restrict__ emb, int n, int Dm1)
{
  int i = blockIdx.x * 256 + threadIdx.x;
  if (i >= n) return;
  float v = sa * a[i];
  if (b) v += b[i];
  v += emb[i & Dm1];
  oF[i] = v; oB[i] = f2bf(v);
}

__global__ __launch_bounds__(256)
void k_gated_add(float* __restrict__ out, const float* __restrict__ h,
                 const float* __restrict__ r, const float* __restrict__ gate, int n, int Dv)
{
  int i = blockIdx.x * 256 + threadIdx.x;
  if (i >= n) return;
  out[i] = h[i] + gate[i / Dv] * r[i];
}

__global__ __launch_bounds__(256)
void k_add2(float* __restrict__ oF, u16* __restrict__ oB,
            const float* __restrict__ a, const float* __restrict__ b, int n)
{
  int i = blockIdx.x * 256 + threadIdx.x;
  if (i >= n) return;
  float v = a[i] + b[i];
  oF[i] = v; oB[i] = f2bf(v);
}

// ---------------- host ----------------
extern "C" void kernel_launch(void* const* d_in, const int* in_sizes, int n_in,
                              void* d_out, int out_size, void* d_ws, size_t ws_size,
                              hipStream_t stream)
{
  (void)in_sizes; (void)n_in; (void)out_size;
  const float* x        = (const float*)d_in[0];
  const float* cache0   = (const float*)d_in[1];
  const float* iter_emb = (const float*)d_in[2];
  const float* rq_w     = (const float*)d_in[3];
  const float* rg_w     = (const float*)d_in[4];
  const float* rg_b     = (const float*)d_in[5];
  const float* ck_w     = (const float*)d_in[6];
  const float* cv_w     = (const float*)d_in[7];
  const float* aq_w     = (const float*)d_in[8];
  const float* ak_w     = (const float*)d_in[9];
  const float* av_w     = (const float*)d_in[10];
  const float* ao_w     = (const float*)d_in[11];
  const float* aq_b     = (const float*)d_in[12];
  const float* ak_b     = (const float*)d_in[13];
  const float* av_b     = (const float*)d_in[14];
  const float* ao_b     = (const float*)d_in[15];
  const float* f1_w     = (const float*)d_in[16];
  const float* f1_b     = (const float*)d_in[17];
  const float* f2_w     = (const float*)d_in[18];
  const float* f2_b     = (const float*)d_in[19];
  const float* n1_g     = (const float*)d_in[20];
  const float* n1_b     = (const float*)d_in[21];
  const float* n2_g     = (const float*)d_in[22];
  const float* n2_b     = (const float*)d_in[23];
  const float* sq_w     = (const float*)d_in[24];
  const float* tk_w     = (const float*)d_in[25];
  const float* tv_w     = (const float*)d_in[26];
  const float* wg_w     = (const float*)d_in[27];
  const float* wg_b     = (const float*)d_in[28];
  const float* cq_w     = (const float*)d_in[29];
  const float* ck2_w    = (const float*)d_in[30];
  const float* cv2_w    = (const float*)d_in[31];
  const float* co_w     = (const float*)d_in[32];
  const float* cq_b     = (const float*)d_in[33];
  const float* ck2_b    = (const float*)d_in[34];
  const float* cv2_b    = (const float*)d_in[35];
  const float* co_b     = (const float*)d_in[36];
  const float* cn_g     = (const float*)d_in[37];
  const float* cn_b     = (const float*)d_in[38];
  // d_in[39] = max_iterations (fixed 2; schedule hardcoded for graph capture)

  float* out = (float*)d_out;

  // -------- workspace carve --------
  size_t off = 0;
  char* base = (char*)d_ws;
  auto allocF = [&](size_t n) { float* p = (float*)(base + off); off += n * 4; off = (off + 255) & ~(size_t)255; return p; };
  auto allocH = [&](size_t n) { u16* p = (u16*)(base + off); off += n * 2; off = (off + 255) & ~(size_t)255; return p; };

  float* hbuf  = allocF((size_t)BS_ * D_);
  float* henh  = allocF((size_t)BS_ * D_);
  float* hcomp = allocF((size_t)BS_ * D_);
  float* h2b   = allocF((size_t)BS_ * D_);
  float* tA    = allocF((size_t)BS_ * D_);
  float* gate  = allocF((size_t)BS_);
  float* ccnf  = allocF((size_t)BNS_ * DS_);
  float* updf  = allocF((size_t)BNS_ * DS_);
  float* coo   = allocF((size_t)BNS_ * DS_);
  float* ccwf  = allocF((size_t)BNS_ * DS_);
  u16* rqT  = allocH((size_t)D_ * D_);
  u16* ckT  = allocH((size_t)D_ * DS_);
  u16* cvT  = allocH((size_t)D_ * DS_);
  u16* aqT  = allocH((size_t)D_ * D_);
  u16* akT  = allocH((size_t)D_ * D_);
  u16* avT  = allocH((size_t)D_ * D_);
  u16* aoT  = allocH((size_t)D_ * D_);
  u16* f1T  = allocH((size_t)DFF_ * D_);
  u16* f2T  = allocH((size_t)D_ * DFF_);
  u16* sqT  = allocH((size_t)DS_ * DS_);
  u16* tkT  = allocH((size_t)DS_ * D_);
  u16* tvTw = allocH((size_t)DS_ * D_);
  u16* cqT  = allocH((size_t)DS_ * DS_);
  u16* ck2T = allocH((size_t)DS_ * DS_);
  u16* cv2T = allocH((size_t)DS_ * DS_);
  u16* coT  = allocH((size_t)DS_ * DS_);
  u16* bb1  = allocH((size_t)BS_ * D_);
  u16* bb2  = allocH((size_t)BS_ * D_);
  u16* bb3  = allocH((size_t)BS_ * D_);
  u16* bb4  = allocH((size_t)BS_ * D_);
  u16* bb5  = allocH((size_t)B_ * H_ * S_ * S_);
  u16* cc0b = allocH((size_t)BNS_ * DS_);
  u16* ccwb = allocH((size_t)BNS_ * DS_);
  u16* sqb  = allocH((size_t)BNS_ * DS_);
  u16* tkb  = allocH((size_t)BS_ * DS_);
  u16* tvTb = allocH((size_t)DS_ * BS_);
  u16* ccnb = allocH((size_t)BNS_ * DS_);
  u16* cqb  = allocH((size_t)BNS_ * DS_);
  u16* ck2b = allocH((size_t)BNS_ * DS_);
  u16* cv2Tb= allocH((size_t)DS_ * BNS_);
  u16* csab = allocH((size_t)BNS_ * DS_);
  if (off > ws_size) return;

  auto gemm = [&](int M, int N, int K, int z, int zdiv,
                  const u16* Ap, int lda, long long sa, long long sa2,
                  const u16* Bq, int ldb, long long sb, long long sb2,
                  float* oF, u16* oB, int ldc, long long sc, long long sc2,
                  u16* oBT, int ldt, long long st, long long st2,
                  const float* bias, const float* rsc, int act) {
    const long long blocks128 = (N % 128 == 0) ? (long long)(N / 128) * (M / 128) * z : 0;
    if (N % 128 == 0 && blocks128 >= 192) {
      dim3 g(N / 128, M / 128, z);
      k_gemm<128, 2, 2><<<g, 256, 0, stream>>>(Ap, lda, sa, sa2, Bq, ldb, sb, sb2,
          oF, oB, ldc, sc, sc2, oBT, ldt, st, st2, K, zdiv, bias, rsc, act);
    } else {
      dim3 g(N / 64, M / 128, z);
      k_gemm<64, 4, 1><<<g, 256, 0, stream>>>(Ap, lda, sa, sa2, Bq, ldb, sb, sb2,
          oF, oB, ldc, sc, sc2, oBT, ldt, st, st2, K, zdiv, bias, rsc, act);
    }
  };
  auto tcvt = [&](const float* in, u16* o, int R, int C) {
    dim3 g(C / 32, R / 32);
    k_tcvt<<<g, 256, 0, stream>>>(in, o, R, C);
  };
  auto lnorm = [&](const float* xp, const float* rp, const float* g, const float* b,
                   float* oF, u16* oB, int rows, int cols) {
    k_layernorm<<<rows, 256, 0, stream>>>(xp, rp, g, b, oF, oB, cols);
  };
  auto eg = [](int n) { return dim3((n + 255) / 256); };

  // ---- weight prep ----
  tcvt(rq_w, rqT, D_, D_);
  tcvt(ck_w, ckT, DS_, D_);
  tcvt(cv_w, cvT, DS_, D_);
  tcvt(aq_w, aqT, D_, D_);
  tcvt(ak_w, akT, D_, D_);
  tcvt(av_w, avT, D_, D_);
  tcvt(ao_w, aoT, D_, D_);
  tcvt(f1_w, f1T, D_, DFF_);
  tcvt(f2_w, f2T, DFF_, D_);
  tcvt(sq_w, sqT, DS_, DS_);
  tcvt(tk_w, tkT, D_, DS_);
  tcvt(tv_w, tvTw, D_, DS_);
  tcvt(cq_w, cqT, DS_, DS_);
  tcvt(ck2_w, ck2T, DS_, DS_);
  tcvt(cv2_w, cv2T, DS_, DS_);
  tcvt(co_w, coT, DS_, DS_);
  k_cvt<<<eg(BNS_ * DS_), 256, 0, stream>>>(cache0, cc0b, BNS_ * DS_);

  // ---- mem_read ----
  auto mem_read = [&](const float* h_f, const u16* h_b, const u16* cc_b, float* o_henh) {
    gemm(BS_, D_, D_, 1, 1, h_b, D_, 0, 0, rqT, D_, 0, 0,
         nullptr, bb2, D_, 0, 0, nullptr, 0, 0, 0, nullptr, nullptr, 0);            // q
    gemm(BNS_, D_, DS_, 1, 1, cc_b, DS_, 0, 0, ckT, DS_, 0, 0,
         nullptr, bb3, D_, 0, 0, nullptr, 0, 0, 0, nullptr, nullptr, 0);            // k
    gemm(BNS_, D_, DS_, 1, 1, cc_b, DS_, 0, 0, cvT, DS_, 0, 0,
         nullptr, nullptr, 0, 0, 0, bb4, BNS_, 0, 0, nullptr, nullptr, 0);          // v^T
    gemm(S_, NSLOT_, D_, B_, 1, bb2, D_, (long long)S_ * D_, 0,
         bb3, D_, (long long)NSLOT_ * D_, 0,
         nullptr, bb5, NSLOT_, (long long)S_ * NSLOT_, 0,
         nullptr, 0, 0, 0, nullptr, nullptr, 0);                                    // q k^T
    k_softmax_b16<<<B_ * S_, 256, 0, stream>>>(bb5, NSLOT_, 0.03125f);
    gemm(S_, D_, NSLOT_, B_, 1, bb5, NSLOT_, (long long)S_ * NSLOT_, 0,
         bb4, BNS_, NSLOT_, 0,
         tA, nullptr, D_, (long long)S_ * D_, 0,
         nullptr, 0, 0, 0, nullptr, nullptr, 0);                                    // readout
    k_gate<<<BS_ / 4, 256, 0, stream>>>(h_f, rg_w, rg_b, gate, D_);
    k_gated_add<<<eg(BS_ * D_), 256, 0, stream>>>(o_henh, h_f, tA, gate, BS_ * D_, D_);
  };

  // ---- compute_block ----
  auto compute_block = [&](const float* he, float* oF, u16* oB) {
    lnorm(he, nullptr, n1_g, n1_b, nullptr, bb1, BS_, D_);
    gemm(BS_, D_, D_, 1, 1, bb1, D_, 0, 0, aqT, D_, 0, 0,
         nullptr, bb2, D_, 0, 0, nullptr, 0, 0, 0, aq_b, nullptr, 0);               // qa
    gemm(BS_, D_, D_, 1, 1, bb1, D_, 0, 0, akT, D_, 0, 0,
         nullptr, bb3, D_, 0, 0, nullptr, 0, 0, 0, ak_b, nullptr, 0);               // ka
    gemm(BS_, D_, D_, 1, 1, bb1, D_, 0, 0, avT, D_, 0, 0,
         nullptr, nullptr, 0, 0, 0, bb4, BS_, 0, 0, av_b, nullptr, 0);              // va^T
    gemm(S_, S_, HD_, B_ * H_, H_,
         bb2, D_, (long long)S_ * D_, HD_,
         bb3, D_, (long long)S_ * D_, HD_,
         nullptr, bb5, S_, (long long)H_ * S_ * S_, (long long)S_ * S_,
         nullptr, 0, 0, 0, nullptr, nullptr, 0);                                    // scores
    k_softmax_b16<<<B_ * H_ * S_, 256, 0, stream>>>(bb5, S_, 0.0625f);
    gemm(S_, HD_, S_, B_ * H_, H_,
         bb5, S_, (long long)H_ * S_ * S_, (long long)S_ * S_,
         bb4, BS_, S_, (long long)HD_ * BS_,
         nullptr, bb2, D_, (long long)S_ * D_, HD_,
         nullptr, 0, 0, 0, nullptr, nullptr, 0);                                    // attnv
    gemm(BS_, D_, D_, 1, 1, bb2, D_, 0, 0, aoT, D_, 0, 0,
         tA, nullptr, D_, 0, 0, nullptr, 0, 0, 0, ao_b, nullptr, 0);                // attno
    lnorm(he, tA, n1_g, n1_b, h2b, bb1, BS_, D_);
    gemm(BS_, DFF_, D_, 1, 1, bb1, D_, 0, 0, f1T, D_, 0, 0,
         nullptr, bb5, DFF_, 0, 0, nullptr, 0, 0, 0, f1_b, nullptr, 1);             // f1+gelu
    gemm(BS_, D_, DFF_, 1, 1, bb5, DFF_, 0, 0, f2T, DFF_, 0, 0,
         tA, nullptr, D_, 0, 0, nullptr, 0, 0, 0, f2_b, nullptr, 0);                // f2
    lnorm(h2b, tA, n2_g, n2_b, oF, oB, BS_, D_);
  };

  // ---- mem_write + cache self-attn (skipped in last iter) ----
  auto mem_write_csa = [&](const float* hc_f, const u16* hc_b,
                           const float* ccin_f, const u16* ccin_b) {
    gemm(BNS_, DS_, DS_, 1, 1, ccin_b, DS_, 0, 0, sqT, DS_, 0, 0,
         nullptr, sqb, DS_, 0, 0, nullptr, 0, 0, 0, nullptr, nullptr, 0);           // sq
    gemm(BS_, DS_, D_, 1, 1, hc_b, D_, 0, 0, tkT, D_, 0, 0,
         nullptr, tkb, DS_, 0, 0, nullptr, 0, 0, 0, nullptr, nullptr, 0);           // tk
    k_gate<<<BS_ / 4, 256, 0, stream>>>(hc_f, wg_w, wg_b, gate, D_);
    gemm(BS_, DS_, D_, 1, 1, hc_b, D_, 0, 0, tvTw, D_, 0, 0,
         nullptr, nullptr, 0, 0, 0, tvTb, BS_, 0, 0, nullptr, gate, 0);             // (gate*tv)^T
    gemm(NSLOT_, S_, DS_, B_, 1, sqb, DS_, (long long)NSLOT_ * DS_, 0,
         tkb, DS_, (long long)S_ * DS_, 0,
         nullptr, bb5, S_, (long long)NSLOT_ * S_, 0,
         nullptr, 0, 0, 0, nullptr, nullptr, 0);                                    // slot scores
    k_softmax_b16<<<B_ * NSLOT_, 256, 0, stream>>>(bb5, S_, 0.05590169943749474f);
    gemm(NSLOT_, DS_, S_, B_, 1, bb5, S_, (long long)NSLOT_ * S_, 0,
         tvTb, BS_, S_, 0,
         updf, nullptr, DS_, (long long)NSLOT_ * DS_, 0,
         nullptr, 0, 0, 0, nullptr, nullptr, 0);                                    // upd
    k_add2<<<eg(BNS_ * DS_), 256, 0, stream>>>(ccnf, ccnb, ccin_f, updf, BNS_ * DS_);
    gemm(BNS_, DS_, DS_, 1, 1, ccnb, DS_, 0, 0, cqT, DS_, 0, 0,
         nullptr, cqb, DS_, 0, 0, nullptr, 0, 0, 0, cq_b, nullptr, 0);              // cq
    gemm(BNS_, DS_, DS_, 1, 1, ccnb, DS_, 0, 0, ck2T, DS_, 0, 0,
         nullptr, ck2b, DS_, 0, 0, nullptr, 0, 0, 0, ck2_b, nullptr, 0);            // ck
    gemm(BNS_, DS_, DS_, 1, 1, ccnb, DS_, 0, 0, cv2T, DS_, 0, 0,
         nullptr, nullptr, 0, 0, 0, cv2Tb, BNS_, 0, 0, cv2_b, nullptr, 0);          // cv^T
    gemm(NSLOT_, NSLOT_, CHD_, B_ * CH_, CH_,
         cqb, DS_, (long long)NSLOT_ * DS_, CHD_,
         ck2b, DS_, (long long)NSLOT_ * DS_, CHD_,
         nullptr, bb5, NSLOT_, (long long)CH_ * NSLOT_ * NSLOT_, (long long)NSLOT_ * NSLOT_,
         nullptr, 0, 0, 0, nullptr, nullptr, 0);                                    // csa scores
    k_softmax_b16<<<B_ * CH_ * NSLOT_, 256, 0, stream>>>(bb5, NSLOT_, 0.125f);
    gemm(NSLOT_, CHD_, NSLOT_, B_ * CH_, CH_,
         bb5, NSLOT_, (long long)CH_ * NSLOT_ * NSLOT_, (long long)NSLOT_ * NSLOT_,
         cv2Tb, BNS_, NSLOT_, (long long)CHD_ * BNS_,
         nullptr, csab, DS_, (long long)NSLOT_ * DS_, CHD_,
         nullptr, 0, 0, 0, nullptr, nullptr, 0);                                    // csa pv
    gemm(BNS_, DS_, DS_, 1, 1, csab, DS_, 0, 0, coT, DS_, 0, 0,
         coo, nullptr, DS_, 0, 0, nullptr, 0, 0, 0, co_b, nullptr, 0);              // co
    lnorm(ccnf, coo, cn_g, cn_b, ccwf, ccwb, BNS_, DS_);
  };

  // ================= iteration 0 =================
  k_combine2<<<eg(BS_ * D_), 256, 0, stream>>>(hbuf, bb1, x, 1.0f, nullptr, iter_emb, BS_ * D_, D_ - 1);
  mem_read(hbuf, bb1, cc0b, henh);
  compute_block(henh, hcomp, bb3);
  mem_write_csa(hcomp, bb3, cache0, cc0b);

  // ================= iteration 1 (last: cache update dead, skipped) =================
  k_combine2<<<eg(BS_ * D_), 256, 0, stream>>>(hbuf, bb1, hcomp, 2.0f, x, iter_emb + D_, BS_ * D_, D_ - 1);
  mem_read(hbuf, bb1, ccwb, henh);
  compute_block(henh, out, nullptr);
}

// Round 5
// 694.547 us; speedup vs baseline: 6.4225x; 1.1023x over previous
//
#include <hip/hip_runtime.h>
#include <cstdint>

// ---------------- problem constants ----------------
constexpr int B_ = 2, S_ = 1024, D_ = 1024, DS_ = 320, NSLOT_ = 512;
constexpr int H_ = 4, CH_ = 5, DFF_ = 4096;
constexpr int HD_ = D_ / H_;      // 256
constexpr int CHD_ = DS_ / CH_;   // 64
constexpr int BS_ = B_ * S_;      // 2048
constexpr int BNS_ = B_ * NSLOT_; // 1024

typedef unsigned short u16;
typedef __attribute__((ext_vector_type(8))) short bf16x8;
typedef __attribute__((ext_vector_type(4))) float f32x4;
typedef __attribute__((ext_vector_type(4))) u16 u16x4;

__device__ __forceinline__ u16 f2bf(float f) {
  unsigned u = __float_as_uint(f);
  return (u16)((u + 0x7FFFu + ((u >> 16) & 1u)) >> 16);  // RNE
}
__device__ __forceinline__ float bf2f(u16 h) { return __uint_as_float((unsigned)h << 16); }

__device__ __forceinline__ void gload16(const void* g, void* l) {
  __builtin_amdgcn_global_load_lds((const __attribute__((address_space(1))) void*)g,
                                   (__attribute__((address_space(3))) void*)l, 16, 0, 0);
}

// ---------------- bf16 MFMA GEMM: C[m,n] = sum_k A[m,k]*B[n,k] ----------------
// BM=128. BN=128 (waves 2x2, 4 stage-loads/step) or BN=64 (waves 4x1, 3 loads).
// BK=32. TRIPLE-buffered LDS, prefetch 2 K-steps ahead, ONE barrier per step,
// counted vmcnt (drain only the oldest batch; vmcnt(0) only on the last step).
// WAR safety with 1 barrier: buffer freed at step i-1 is restaged at step i;
// a wave passing barrier(i) has consumed all its step i-1 ds_reads.
// XOR-swizzled LDS (linear gload dest, pre-swizzled global source granule,
// same involution on fragment read) -> 0 bank conflicts (verified r3).
template<int BN, int WM, int WN>
__global__ __launch_bounds__(256)
void k_gemm(const u16* __restrict__ A, int lda, long long sA, long long sA2,
            const u16* __restrict__ Bp, int ldb, long long sB, long long sB2,
            float* __restrict__ outF, u16* __restrict__ outB,
            int ldc, long long sC, long long sC2,
            u16* __restrict__ outBT, int ldt, long long sT, long long sT2,
            int K, int zdiv, const float* __restrict__ bias,
            const float* __restrict__ rowscale, int act)
{
  constexpr int BM = 128;
  constexpr int MI = BM / (WM * 16);
  constexpr int NI = BN / (WN * 16);
  constexpr int ABYT = BM * 64;            // bytes per A K-tile (BK=32 bf16 = 64B/row)
  constexpr int BBYT = BN * 64;
  constexpr int BUF = ABYT + BBYT;
  const int z = blockIdx.z, zb = z / zdiv, zr = z - zb * zdiv;
  A  += (long long)zb * sA + (long long)zr * sA2;
  Bp += (long long)zb * sB + (long long)zr * sB2;
  const long long cof = (long long)zb * sC + (long long)zr * sC2;
  const long long tof = (long long)zb * sT + (long long)zr * sT2;
  const int bm = blockIdx.y * BM, bn = blockIdx.x * BN;
  __shared__ __align__(16) char lds[3 * BUF];
  const int tid = threadIdx.x;
  const int lane = tid & 63, wid = tid >> 6;
  const int wm = wid / WN, wn = wid - wm * WN;
  const int rowb = wm * (BM / WM), colb = wn * (BN / WN);

  f32x4 acc[MI][NI];
  const f32x4 fz = {0.f, 0.f, 0.f, 0.f};
  #pragma unroll
  for (int i = 0; i < MI; ++i)
    #pragma unroll
    for (int j = 0; j < NI; ++j) acc[i][j] = fz;

  // staging: thread t -> row t>>2, LDS granule p=t&3 (linear dest = lane*16);
  // source granule = p ^ ((row>>1)&3) = p ^ ((t>>3)&3)
  const int srow = tid >> 2;
  const int sgr  = (tid & 3) ^ ((tid >> 3) & 3);
  const u16* gA = A + (long long)(bm + srow) * lda + sgr * 8;
  const u16* gB = Bp + (long long)(bn + srow) * ldb + sgr * 8;

  // fragment read: row base + (lane&15), logical granule q=lane>>4 at q ^ ((r>>1)&3)
  const int r = lane & 15, q = lane >> 4;
  const int sa_off = (rowb + r) * 64 + ((q ^ ((r >> 1) & 3)) << 4);
  const int sb_off = (colb + r) * 64 + ((q ^ ((r >> 1) & 3)) << 4);

  auto stage = [&](int buf, int k0) {
    char* la = lds + buf * BUF + wid * 1024;
    char* lb = lds + buf * BUF + ABYT + wid * 1024;
    gload16(gA + k0, la);
    gload16(gA + (long long)64 * lda + k0, la + 4096);
    gload16(gB + k0, lb);
    if constexpr (BN == 128) gload16(gB + (long long)64 * ldb + k0, lb + 4096);
  };

  const int nsteps = K >> 5;
  stage(0, 0);
  if (nsteps > 1) stage(1, 32);
  int cur = 0;
  for (int i = 0; i < nsteps; ++i) {
    // wait for buf[cur]'s loads (oldest batch); keep the newer batch in flight
    if (i == nsteps - 1) {
      asm volatile("s_waitcnt vmcnt(0)" ::: "memory");
    } else if constexpr (BN == 128) {
      asm volatile("s_waitcnt vmcnt(4)" ::: "memory");
    } else {
      asm volatile("s_waitcnt vmcnt(3)" ::: "memory");
    }
    __builtin_amdgcn_s_barrier();          // everyone's buf[cur] landed; step i-1 reads done
    __builtin_amdgcn_sched_barrier(0);
    if (i + 2 < nsteps) {
      int sb = cur + 2; if (sb >= 3) sb -= 3;
      stage(sb, (i + 2) << 5);             // restage buffer freed at step i-1
    }
    const char* pa = lds + cur * BUF + sa_off;
    const char* pb = lds + cur * BUF + ABYT + sb_off;
    bf16x8 af[MI], bv[NI];
    #pragma unroll
    for (int ii = 0; ii < MI; ++ii) af[ii] = *(const bf16x8*)(pa + ii * 1024);
    #pragma unroll
    for (int jj = 0; jj < NI; ++jj) bv[jj] = *(const bf16x8*)(pb + jj * 1024);
    #pragma unroll
    for (int ii = 0; ii < MI; ++ii)
      #pragma unroll
      for (int jj = 0; jj < NI; ++jj)
        acc[ii][jj] = __builtin_amdgcn_mfma_f32_16x16x32_bf16(af[ii], bv[jj], acc[ii][jj], 0, 0, 0);
    cur = (cur == 2) ? 0 : cur + 1;
  }

  const int fr = lane & 15, fq = lane >> 4;
  #pragma unroll
  for (int i = 0; i < MI; ++i) {
    const int r0 = bm + rowb + i * 16 + fq * 4;
    #pragma unroll
    for (int j = 0; j < NI; ++j) {
      const int cn = bn + colb + j * 16 + fr;
      const float bvv = bias ? bias[cn] : 0.f;
      float vv[4];
      #pragma unroll
      for (int t = 0; t < 4; ++t) {
        float v = acc[i][j][t] + bvv;
        if (rowscale) v *= rowscale[r0 + t];
        if (act) v = 0.5f * v * (1.f + tanhf(0.7978845608028654f * (v + 0.044715f * v * v * v)));
        vv[t] = v;
      }
      if (outF) {
        #pragma unroll
        for (int t = 0; t < 4; ++t) outF[cof + (long long)(r0 + t) * ldc + cn] = vv[t];
      }
      if (outB) {
        #pragma unroll
        for (int t = 0; t < 4; ++t) outB[cof + (long long)(r0 + t) * ldc + cn] = f2bf(vv[t]);
      }
      if (outBT) {
        u16x4 pk = {f2bf(vv[0]), f2bf(vv[1]), f2bf(vv[2]), f2bf(vv[3])};
        *(u16x4*)(outBT + tof + (long long)cn * ldt + r0) = pk;
      }
    }
  }
}

// ---------------- transpose + convert: in[R][C] fp32 -> out[C][R] bf16 ----------------
__global__ __launch_bounds__(256)
void k_tcvt(const float* __restrict__ in, u16* __restrict__ out, int R, int C)
{
  __shared__ float t[32][33];
  const int bx = blockIdx.x * 32, by = blockIdx.y * 32;
  const int tx = threadIdx.x & 31, ty = threadIdx.x >> 5;
  #pragma unroll
  for (int i = 0; i < 32; i += 8)
    t[ty + i][tx] = in[(long long)(by + ty + i) * C + bx + tx];
  __syncthreads();
  #pragma unroll
  for (int i = 0; i < 32; i += 8)
    out[(long long)(bx + ty + i) * R + by + tx] = f2bf(t[tx][ty + i]);
}

// ---------------- convert fp32 -> bf16 ----------------
__global__ __launch_bounds__(256)
void k_cvt(const float* __restrict__ in, u16* __restrict__ out, int n)
{
  int i = blockIdx.x * 256 + threadIdx.x;
  if (i < n) out[i] = f2bf(in[i]);
}

// ---------------- row softmax on bf16 in place (cols <= 1024) ----------------
__global__ __launch_bounds__(256)
void k_softmax_b16(u16* __restrict__ x, int cols, float scale)
{
  u16* p = x + (long long)blockIdx.x * cols;
  const int tid = threadIdx.x;
  __shared__ float red[256];
  float v[4];
  float m = -1e30f;
  #pragma unroll
  for (int i = 0; i < 4; ++i) {
    const int c = tid + (i << 8);
    v[i] = (c < cols) ? bf2f(p[c]) * scale : -1e30f;
    m = fmaxf(m, v[i]);
  }
  red[tid] = m; __syncthreads();
  for (int s = 128; s > 0; s >>= 1) { if (tid < s) red[tid] = fmaxf(red[tid], red[tid + s]); __syncthreads(); }
  m = red[0]; __syncthreads();
  float sum = 0.f;
  #pragma unroll
  for (int i = 0; i < 4; ++i) { v[i] = expf(v[i] - m); sum += v[i]; }
  red[tid] = sum; __syncthreads();
  for (int s = 128; s > 0; s >>= 1) { if (tid < s) red[tid] += red[tid + s]; __syncthreads(); }
  const float inv = 1.f / red[0];
  #pragma unroll
  for (int i = 0; i < 4; ++i) {
    const int c = tid + (i << 8);
    if (c < cols) p[c] = f2bf(v[i] * inv);
  }
}

// ---------------- layernorm: LN(x [+res])*g + b -> fp32 out (opt) + bf16 out (opt) ----------------
__global__ __launch_bounds__(256)
void k_layernorm(const float* __restrict__ x, const float* __restrict__ res,
                 const float* __restrict__ g, const float* __restrict__ b,
                 float* __restrict__ outF, u16* __restrict__ outB, int cols)
{
  const long long ro = (long long)blockIdx.x * cols;
  const float* px = x + ro;
  const float* pr = res ? res + ro : nullptr;
  __shared__ float red[256];
  const int tid = threadIdx.x;
  float s = 0.f;
  for (int c = tid; c < cols; c += 256) { float v = px[c] + (pr ? pr[c] : 0.f); s += v; }
  red[tid] = s; __syncthreads();
  for (int t = 128; t > 0; t >>= 1) { if (tid < t) red[tid] += red[tid + t]; __syncthreads(); }
  const float mean = red[0] / cols; __syncthreads();
  float s2 = 0.f;
  for (int c = tid; c < cols; c += 256) { float v = px[c] + (pr ? pr[c] : 0.f) - mean; s2 += v * v; }
  red[tid] = s2; __syncthreads();
  for (int t = 128; t > 0; t >>= 1) { if (tid < t) red[tid] += red[tid + t]; __syncthreads(); }
  const float inv = rsqrtf(red[0] / cols + 1e-5f);
  for (int c = tid; c < cols; c += 256) {
    float v = (px[c] + (pr ? pr[c] : 0.f) - mean) * inv * g[c] + b[c];
    if (outF) outF[ro + c] = v;
    if (outB) outB[ro + c] = f2bf(v);
  }
}

// ---------------- gate[row] = sigmoid(dot(x[row], w) + b0), 1 wave / row ----------------
__global__ __launch_bounds__(256)
void k_gate(const float* __restrict__ x, const float* __restrict__ w,
            const float* __restrict__ b0, float* __restrict__ out, int cols)
{
  const int lane = threadIdx.x & 63;
  const int wv = threadIdx.x >> 6;
  const long long row = (long long)blockIdx.x * 4 + wv;
  const float* p = x + row * cols;
  float s = 0.f;
  for (int c = lane; c < cols; c += 64) s += p[c] * w[c];
  #pragma unroll
  for (int off = 32; off > 0; off >>= 1) s += __shfl_down(s, off);
  if (lane == 0) out[row] = 1.0f / (1.0f + expf(-(s + b0[0])));
}

// ---------------- elementwise ----------------
__global__ __launch_bounds__(256)
void k_combine2(float* __restrict__ oF, u16* __restrict__ oB,
                const float* __restrict__ a, float sa, const float* __restrict__ b,
                const float* __restrict__ emb, int n, int Dm1)
{
  int i = blockIdx.x * 256 + threadIdx.x;
  if (i >= n) return;
  float v = sa * a[i];
  if (b) v += b[i];
  v += emb[i & Dm1];
  oF[i] = v; oB[i] = f2bf(v);
}

__global__ __launch_bounds__(256)
void k_gated_add(float* __restrict__ out, const float* __restrict__ h,
                 const float* __restrict__ r, const float* __restrict__ gate, int n, int Dv)
{
  int i = blockIdx.x * 256 + threadIdx.x;
  if (i >= n) return;
  out[i] = h[i] + gate[i / Dv] * r[i];
}

__global__ __launch_bounds__(256)
void k_add2(float* __restrict__ oF, u16* __restrict__ oB,
            const float* __restrict__ a, const float* __restrict__ b, int n)
{
  int i = blockIdx.x * 256 + threadIdx.x;
  if (i >= n) return;
  float v = a[i] + b[i];
  oF[i] = v; oB[i] = f2bf(v);
}

// ---------------- host ----------------
extern "C" void kernel_launch(void* const* d_in, const int* in_sizes, int n_in,
                              void* d_out, int out_size, void* d_ws, size_t ws_size,
                              hipStream_t stream)
{
  (void)in_sizes; (void)n_in; (void)out_size;
  const float* x        = (const float*)d_in[0];
  const float* cache0   = (const float*)d_in[1];
  const float* iter_emb = (const float*)d_in[2];
  const float* rq_w     = (const float*)d_in[3];
  const float* rg_w     = (const float*)d_in[4];
  const float* rg_b     = (const float*)d_in[5];
  const float* ck_w     = (const float*)d_in[6];
  const float* cv_w     = (const float*)d_in[7];
  const float* aq_w     = (const float*)d_in[8];
  const float* ak_w     = (const float*)d_in[9];
  const float* av_w     = (const float*)d_in[10];
  const float* ao_w     = (const float*)d_in[11];
  const float* aq_b     = (const float*)d_in[12];
  const float* ak_b     = (const float*)d_in[13];
  const float* av_b     = (const float*)d_in[14];
  const float* ao_b     = (const float*)d_in[15];
  const float* f1_w     = (const float*)d_in[16];
  const float* f1_b     = (const float*)d_in[17];
  const float* f2_w     = (const float*)d_in[18];
  const float* f2_b     = (const float*)d_in[19];
  const float* n1_g     = (const float*)d_in[20];
  const float* n1_b     = (const float*)d_in[21];
  const float* n2_g     = (const float*)d_in[22];
  const float* n2_b     = (const float*)d_in[23];
  const float* sq_w     = (const float*)d_in[24];
  const float* tk_w     = (const float*)d_in[25];
  const float* tv_w     = (const float*)d_in[26];
  const float* wg_w     = (const float*)d_in[27];
  const float* wg_b     = (const float*)d_in[28];
  const float* cq_w     = (const float*)d_in[29];
  const float* ck2_w    = (const float*)d_in[30];
  const float* cv2_w    = (const float*)d_in[31];
  const float* co_w     = (const float*)d_in[32];
  const float* cq_b     = (const float*)d_in[33];
  const float* ck2_b    = (const float*)d_in[34];
  const float* cv2_b    = (const float*)d_in[35];
  const float* co_b     = (const float*)d_in[36];
  const float* cn_g     = (const float*)d_in[37];
  const float* cn_b     = (const float*)d_in[38];
  // d_in[39] = max_iterations (fixed 2; schedule hardcoded for graph capture)

  float* out = (float*)d_out;

  // -------- workspace carve --------
  size_t off = 0;
  char* base = (char*)d_ws;
  auto allocF = [&](size_t n) { float* p = (float*)(base + off); off += n * 4; off = (off + 255) & ~(size_t)255; return p; };
  auto allocH = [&](size_t n) { u16* p = (u16*)(base + off); off += n * 2; off = (off + 255) & ~(size_t)255; return p; };

  float* hbuf  = allocF((size_t)BS_ * D_);
  float* henh  = allocF((size_t)BS_ * D_);
  float* hcomp = allocF((size_t)BS_ * D_);
  float* h2b   = allocF((size_t)BS_ * D_);
  float* tA    = allocF((size_t)BS_ * D_);
  float* gate  = allocF((size_t)BS_);
  float* ccnf  = allocF((size_t)BNS_ * DS_);
  float* updf  = allocF((size_t)BNS_ * DS_);
  float* coo   = allocF((size_t)BNS_ * DS_);
  float* ccwf  = allocF((size_t)BNS_ * DS_);
  u16* rqT  = allocH((size_t)D_ * D_);
  u16* ckT  = allocH((size_t)D_ * DS_);
  u16* cvT  = allocH((size_t)D_ * DS_);
  u16* aqT  = allocH((size_t)D_ * D_);
  u16* akT  = allocH((size_t)D_ * D_);
  u16* avT  = allocH((size_t)D_ * D_);
  u16* aoT  = allocH((size_t)D_ * D_);
  u16* f1T  = allocH((size_t)DFF_ * D_);
  u16* f2T  = allocH((size_t)D_ * DFF_);
  u16* sqT  = allocH((size_t)DS_ * DS_);
  u16* tkT  = allocH((size_t)DS_ * D_);
  u16* tvTw = allocH((size_t)DS_ * D_);
  u16* cqT  = allocH((size_t)DS_ * DS_);
  u16* ck2T = allocH((size_t)DS_ * DS_);
  u16* cv2T = allocH((size_t)DS_ * DS_);
  u16* coT  = allocH((size_t)DS_ * DS_);
  u16* bb1  = allocH((size_t)BS_ * D_);
  u16* bb2  = allocH((size_t)BS_ * D_);
  u16* bb3  = allocH((size_t)BS_ * D_);
  u16* bb4  = allocH((size_t)BS_ * D_);
  u16* bb5  = allocH((size_t)B_ * H_ * S_ * S_);
  u16* cc0b = allocH((size_t)BNS_ * DS_);
  u16* ccwb = allocH((size_t)BNS_ * DS_);
  u16* sqb  = allocH((size_t)BNS_ * DS_);
  u16* tkb  = allocH((size_t)BS_ * DS_);
  u16* tvTb = allocH((size_t)DS_ * BS_);
  u16* ccnb = allocH((size_t)BNS_ * DS_);
  u16* cqb  = allocH((size_t)BNS_ * DS_);
  u16* ck2b = allocH((size_t)BNS_ * DS_);
  u16* cv2Tb= allocH((size_t)DS_ * BNS_);
  u16* csab = allocH((size_t)BNS_ * DS_);
  if (off > ws_size) return;

  auto gemm = [&](int M, int N, int K, int z, int zdiv,
                  const u16* Ap, int lda, long long sa, long long sa2,
                  const u16* Bq, int ldb, long long sb, long long sb2,
                  float* oF, u16* oB, int ldc, long long sc, long long sc2,
                  u16* oBT, int ldt, long long st, long long st2,
                  const float* bias, const float* rsc, int act) {
    const long long blocks128 = (N % 128 == 0) ? (long long)(N / 128) * (M / 128) * z : 0;
    if (N % 128 == 0 && blocks128 >= 192) {
      dim3 g(N / 128, M / 128, z);
      k_gemm<128, 2, 2><<<g, 256, 0, stream>>>(Ap, lda, sa, sa2, Bq, ldb, sb, sb2,
          oF, oB, ldc, sc, sc2, oBT, ldt, st, st2, K, zdiv, bias, rsc, act);
    } else {
      dim3 g(N / 64, M / 128, z);
      k_gemm<64, 4, 1><<<g, 256, 0, stream>>>(Ap, lda, sa, sa2, Bq, ldb, sb, sb2,
          oF, oB, ldc, sc, sc2, oBT, ldt, st, st2, K, zdiv, bias, rsc, act);
    }
  };
  auto tcvt = [&](const float* in, u16* o, int R, int C) {
    dim3 g(C / 32, R / 32);
    k_tcvt<<<g, 256, 0, stream>>>(in, o, R, C);
  };
  auto lnorm = [&](const float* xp, const float* rp, const float* g, const float* b,
                   float* oF, u16* oB, int rows, int cols) {
    k_layernorm<<<rows, 256, 0, stream>>>(xp, rp, g, b, oF, oB, cols);
  };
  auto eg = [](int n) { return dim3((n + 255) / 256); };

  // ---- weight prep ----
  tcvt(rq_w, rqT, D_, D_);
  tcvt(ck_w, ckT, DS_, D_);
  tcvt(cv_w, cvT, DS_, D_);
  tcvt(aq_w, aqT, D_, D_);
  tcvt(ak_w, akT, D_, D_);
  tcvt(av_w, avT, D_, D_);
  tcvt(ao_w, aoT, D_, D_);
  tcvt(f1_w, f1T, D_, DFF_);
  tcvt(f2_w, f2T, DFF_, D_);
  tcvt(sq_w, sqT, DS_, DS_);
  tcvt(tk_w, tkT, D_, DS_);
  tcvt(tv_w, tvTw, D_, DS_);
  tcvt(cq_w, cqT, DS_, DS_);
  tcvt(ck2_w, ck2T, DS_, DS_);
  tcvt(cv2_w, cv2T, DS_, DS_);
  tcvt(co_w, coT, DS_, DS_);
  k_cvt<<<eg(BNS_ * DS_), 256, 0, stream>>>(cache0, cc0b, BNS_ * DS_);

  // ---- mem_read ----
  auto mem_read = [&](const float* h_f, const u16* h_b, const u16* cc_b, float* o_henh) {
    gemm(BS_, D_, D_, 1, 1, h_b, D_, 0, 0, rqT, D_, 0, 0,
         nullptr, bb2, D_, 0, 0, nullptr, 0, 0, 0, nullptr, nullptr, 0);            // q
    gemm(BNS_, D_, DS_, 1, 1, cc_b, DS_, 0, 0, ckT, DS_, 0, 0,
         nullptr, bb3, D_, 0, 0, nullptr, 0, 0, 0, nullptr, nullptr, 0);            // k
    gemm(BNS_, D_, DS_, 1, 1, cc_b, DS_, 0, 0, cvT, DS_, 0, 0,
         nullptr, nullptr, 0, 0, 0, bb4, BNS_, 0, 0, nullptr, nullptr, 0);          // v^T
    gemm(S_, NSLOT_, D_, B_, 1, bb2, D_, (long long)S_ * D_, 0,
         bb3, D_, (long long)NSLOT_ * D_, 0,
         nullptr, bb5, NSLOT_, (long long)S_ * NSLOT_, 0,
         nullptr, 0, 0, 0, nullptr, nullptr, 0);                                    // q k^T
    k_softmax_b16<<<B_ * S_, 256, 0, stream>>>(bb5, NSLOT_, 0.03125f);
    gemm(S_, D_, NSLOT_, B_, 1, bb5, NSLOT_, (long long)S_ * NSLOT_, 0,
         bb4, BNS_, NSLOT_, 0,
         tA, nullptr, D_, (long long)S_ * D_, 0,
         nullptr, 0, 0, 0, nullptr, nullptr, 0);                                    // readout
    k_gate<<<BS_ / 4, 256, 0, stream>>>(h_f, rg_w, rg_b, gate, D_);
    k_gated_add<<<eg(BS_ * D_), 256, 0, stream>>>(o_henh, h_f, tA, gate, BS_ * D_, D_);
  };

  // ---- compute_block ----
  auto compute_block = [&](const float* he, float* oF, u16* oB) {
    lnorm(he, nullptr, n1_g, n1_b, nullptr, bb1, BS_, D_);
    gemm(BS_, D_, D_, 1, 1, bb1, D_, 0, 0, aqT, D_, 0, 0,
         nullptr, bb2, D_, 0, 0, nullptr, 0, 0, 0, aq_b, nullptr, 0);               // qa
    gemm(BS_, D_, D_, 1, 1, bb1, D_, 0, 0, akT, D_, 0, 0,
         nullptr, bb3, D_, 0, 0, nullptr, 0, 0, 0, ak_b, nullptr, 0);               // ka
    gemm(BS_, D_, D_, 1, 1, bb1, D_, 0, 0, avT, D_, 0, 0,
         nullptr, nullptr, 0, 0, 0, bb4, BS_, 0, 0, av_b, nullptr, 0);              // va^T
    gemm(S_, S_, HD_, B_ * H_, H_,
         bb2, D_, (long long)S_ * D_, HD_,
         bb3, D_, (long long)S_ * D_, HD_,
         nullptr, bb5, S_, (long long)H_ * S_ * S_, (long long)S_ * S_,
         nullptr, 0, 0, 0, nullptr, nullptr, 0);                                    // scores
    k_softmax_b16<<<B_ * H_ * S_, 256, 0, stream>>>(bb5, S_, 0.0625f);
    gemm(S_, HD_, S_, B_ * H_, H_,
         bb5, S_, (long long)H_ * S_ * S_, (long long)S_ * S_,
         bb4, BS_, S_, (long long)HD_ * BS_,
         nullptr, bb2, D_, (long long)S_ * D_, HD_,
         nullptr, 0, 0, 0, nullptr, nullptr, 0);                                    // attnv
    gemm(BS_, D_, D_, 1, 1, bb2, D_, 0, 0, aoT, D_, 0, 0,
         tA, nullptr, D_, 0, 0, nullptr, 0, 0, 0, ao_b, nullptr, 0);                // attno
    lnorm(he, tA, n1_g, n1_b, h2b, bb1, BS_, D_);
    gemm(BS_, DFF_, D_, 1, 1, bb1, D_, 0, 0, f1T, D_, 0, 0,
         nullptr, bb5, DFF_, 0, 0, nullptr, 0, 0, 0, f1_b, nullptr, 1);             // f1+gelu
    gemm(BS_, D_, DFF_, 1, 1, bb5, DFF_, 0, 0, f2T, DFF_, 0, 0,
         tA, nullptr, D_, 0, 0, nullptr, 0, 0, 0, f2_b, nullptr, 0);                // f2
    lnorm(h2b, tA, n2_g, n2_b, oF, oB, BS_, D_);
  };

  // ---- mem_write + cache self-attn (skipped in last iter) ----
  auto mem_write_csa = [&](const float* hc_f, const u16* hc_b,
                           const float* ccin_f, const u16* ccin_b) {
    gemm(BNS_, DS_, DS_, 1, 1, ccin_b, DS_, 0, 0, sqT, DS_, 0, 0,
         nullptr, sqb, DS_, 0, 0, nullptr, 0, 0, 0, nullptr, nullptr, 0);           // sq
    gemm(BS_, DS_, D_, 1, 1, hc_b, D_, 0, 0, tkT, D_, 0, 0,
         nullptr, tkb, DS_, 0, 0, nullptr, 0, 0, 0, nullptr, nullptr, 0);           // tk
    k_gate<<<BS_ / 4, 256, 0, stream>>>(hc_f, wg_w, wg_b, gate, D_);
    gemm(BS_, DS_, D_, 1, 1, hc_b, D_, 0, 0, tvTw, D_, 0, 0,
         nullptr, nullptr, 0, 0, 0, tvTb, BS_, 0, 0, nullptr, gate, 0);             // (gate*tv)^T
    gemm(NSLOT_, S_, DS_, B_, 1, sqb, DS_, (long long)NSLOT_ * DS_, 0,
         tkb, DS_, (long long)S_ * DS_, 0,
         nullptr, bb5, S_, (long long)NSLOT_ * S_, 0,
         nullptr, 0, 0, 0, nullptr, nullptr, 0);                                    // slot scores
    k_softmax_b16<<<B_ * NSLOT_, 256, 0, stream>>>(bb5, S_, 0.05590169943749474f);
    gemm(NSLOT_, DS_, S_, B_, 1, bb5, S_, (long long)NSLOT_ * S_, 0,
         tvTb, BS_, S_, 0,
         updf, nullptr, DS_, (long long)NSLOT_ * DS_, 0,
         nullptr, 0, 0, 0, nullptr, nullptr, 0);                                    // upd
    k_add2<<<eg(BNS_ * DS_), 256, 0, stream>>>(ccnf, ccnb, ccin_f, updf, BNS_ * DS_);
    gemm(BNS_, DS_, DS_, 1, 1, ccnb, DS_, 0, 0, cqT, DS_, 0, 0,
         nullptr, cqb, DS_, 0, 0, nullptr, 0, 0, 0, cq_b, nullptr, 0);              // cq
    gemm(BNS_, DS_, DS_, 1, 1, ccnb, DS_, 0, 0, ck2T, DS_, 0, 0,
         nullptr, ck2b, DS_, 0, 0, nullptr, 0, 0, 0, ck2_b, nullptr, 0);            // ck
    gemm(BNS_, DS_, DS_, 1, 1, ccnb, DS_, 0, 0, cv2T, DS_, 0, 0,
         nullptr, nullptr, 0, 0, 0, cv2Tb, BNS_, 0, 0, cv2_b, nullptr, 0);          // cv^T
    gemm(NSLOT_, NSLOT_, CHD_, B_ * CH_, CH_,
         cqb, DS_, (long long)NSLOT_ * DS_, CHD_,
         ck2b, DS_, (long long)NSLOT_ * DS_, CHD_,
         nullptr, bb5, NSLOT_, (long long)CH_ * NSLOT_ * NSLOT_, (long long)NSLOT_ * NSLOT_,
         nullptr, 0, 0, 0, nullptr, nullptr, 0);                                    // csa scores
    k_softmax_b16<<<B_ * CH_ * NSLOT_, 256, 0, stream>>>(bb5, NSLOT_, 0.125f);
    gemm(NSLOT_, CHD_, NSLOT_, B_ * CH_, CH_,
         bb5, NSLOT_, (long long)CH_ * NSLOT_ * NSLOT_, (long long)NSLOT_ * NSLOT_,
         cv2Tb, BNS_, NSLOT_, (long long)CHD_ * BNS_,
         nullptr, csab, DS_, (long long)NSLOT_ * DS_, CHD_,
         nullptr, 0, 0, 0, nullptr, nullptr, 0);                                    // csa pv
    gemm(BNS_, DS_, DS_, 1, 1, csab, DS_, 0, 0, coT, DS_, 0, 0,
         coo, nullptr, DS_, 0, 0, nullptr, 0, 0, 0, co_b, nullptr, 0);              // co
    lnorm(ccnf, coo, cn_g, cn_b, ccwf, ccwb, BNS_, DS_);
  };

  // ================= iteration 0 =================
  k_combine2<<<eg(BS_ * D_), 256, 0, stream>>>(hbuf, bb1, x, 1.0f, nullptr, iter_emb, BS_ * D_, D_ - 1);
  mem_read(hbuf, bb1, cc0b, henh);
  compute_block(henh, hcomp, bb3);
  mem_write_csa(hcomp, bb3, cache0, cc0b);

  // ================= iteration 1 (last: cache update dead, skipped) =================
  k_combine2<<<eg(BS_ * D_), 256, 0, stream>>>(hbuf, bb1, hcomp, 2.0f, x, iter_emb + D_, BS_ * D_, D_ - 1);
  mem_read(hbuf, bb1, ccwb, henh);
  compute_block(henh, out, nullptr);
}

// Round 6
// 625.007 us; speedup vs baseline: 7.1371x; 1.1113x over previous
//
#include <hip/hip_runtime.h>
#include <cstdint>

// ---------------- problem constants ----------------
constexpr int B_ = 2, S_ = 1024, D_ = 1024, DS_ = 320, NSLOT_ = 512;
constexpr int H_ = 4, CH_ = 5, DFF_ = 4096;
constexpr int HD_ = D_ / H_;      // 256
constexpr int CHD_ = DS_ / CH_;   // 64
constexpr int BS_ = B_ * S_;      // 2048
constexpr int BNS_ = B_ * NSLOT_; // 1024

typedef unsigned short u16;
typedef __attribute__((ext_vector_type(8))) short bf16x8;
typedef __attribute__((ext_vector_type(4))) float f32x4;
typedef __attribute__((ext_vector_type(4))) u16 u16x4;

__device__ __forceinline__ u16 f2bf(float f) {
  unsigned u = __float_as_uint(f);
  return (u16)((u + 0x7FFFu + ((u >> 16) & 1u)) >> 16);  // RNE
}
__device__ __forceinline__ float bf2f(u16 h) { return __uint_as_float((unsigned)h << 16); }

__device__ __forceinline__ void gload16(const void* g, void* l) {
  __builtin_amdgcn_global_load_lds((const __attribute__((address_space(1))) void*)g,
                                   (__attribute__((address_space(3))) void*)l, 16, 0, 0);
}

// ---------------- bf16 MFMA GEMM: C[m,n] = sum_k A[m,k]*B[n,k] ----------------
// BM=128, BK=64, 512 threads (8 waves). BN=128: waves 4x2 (per-wave 32x64);
// BN=64: waves 8x1 (per-wave 16x64). Double-buffered, counted vmcnt.
// 8 waves/block * 2 blocks/CU = 4 waves/SIMD for latency hiding (TLP).
// LDS rows are 128B (64 bf16); XOR swizzle granule g^=(row&7): per-16-lane
// phase each bank-quad served exactly 2 lanes -> conflict-free.
// global_load_lds dest is linear (wave-uniform base + lane*16); the SOURCE
// granule is pre-swizzled with the same involution; reads apply it too.
template<int BN>
__global__ __launch_bounds__(512, 4)
void k_gemm(const u16* __restrict__ A, int lda, long long sA, long long sA2,
            const u16* __restrict__ Bp, int ldb, long long sB, long long sB2,
            float* __restrict__ outF, u16* __restrict__ outB,
            int ldc, long long sC, long long sC2,
            u16* __restrict__ outBT, int ldt, long long sT, long long sT2,
            int K, int zdiv, const float* __restrict__ bias,
            const float* __restrict__ rowscale, int act)
{
  constexpr int BM = 128;
  constexpr int MI = (BN == 128) ? 2 : 1;   // 16-row frags per wave
  constexpr int NI = 4;                     // 16-col frags per wave (64 cols)
  constexpr int WROWS = MI * 16;
  constexpr int ABYT = BM * 128;            // 16 KB (128 rows x 64 bf16)
  constexpr int BBYT = BN * 128;
  constexpr int BUF = ABYT + BBYT;
  const int z = blockIdx.z, zb = z / zdiv, zr = z - zb * zdiv;
  A  += (long long)zb * sA + (long long)zr * sA2;
  Bp += (long long)zb * sB + (long long)zr * sB2;
  const long long cof = (long long)zb * sC + (long long)zr * sC2;
  const long long tof = (long long)zb * sT + (long long)zr * sT2;
  const int bm = blockIdx.y * BM, bn = blockIdx.x * BN;
  __shared__ __align__(16) char lds[2 * BUF];
  const int tid = threadIdx.x;
  const int lane = tid & 63, wid = tid >> 6;
  const int wm = (BN == 128) ? (wid >> 1) : wid;
  const int wn = (BN == 128) ? (wid & 1) : 0;
  const int rowb = wm * WROWS, colb = wn * 64;

  f32x4 acc[MI][NI];
  const f32x4 fz = {0.f, 0.f, 0.f, 0.f};
  #pragma unroll
  for (int i = 0; i < MI; ++i)
    #pragma unroll
    for (int j = 0; j < NI; ++j) acc[i][j] = fz;

  // staging: thread t -> LDS granule t (and t+512 for the 2nd A/B chunk).
  // row = t>>3; source granule = (t&7) ^ (row&7)  (same for row+64).
  const int trow = tid >> 3;
  const int tg   = ((tid & 7) ^ (trow & 7)) * 8;   // element offset in row
  const u16* gA  = A + (long long)(bm + trow) * lda + tg;
  const u16* gA2 = gA + (long long)64 * lda;
  const u16* gB  = Bp + (long long)(bn + trow) * ldb + tg;
  const u16* gB2 = gB + (long long)64 * ldb;       // used only when BN==128

  auto stage = [&](int buf, int k0) {
    char* la = lds + buf * BUF + wid * 1024;
    char* lb = lds + buf * BUF + ABYT + wid * 1024;
    gload16(gA + k0, la);
    gload16(gA2 + k0, la + 8192);
    gload16(gB + k0, lb);
    if constexpr (BN == 128) gload16(gB2 + k0, lb + 8192);
  };

  // fragment read offsets: row' = base + i*16 + r; granule (4s+q) ^ (r&7)
  const int r = lane & 15, q = lane >> 4;
  const int c7 = r & 7;
  const int gs0 = ((q) ^ c7) << 4;
  const int gs1 = ((4 + q) ^ c7) << 4;
  int aoff[MI], boff[NI];
  #pragma unroll
  for (int i = 0; i < MI; ++i) aoff[i] = (rowb + i * 16 + r) * 128;
  #pragma unroll
  for (int j = 0; j < NI; ++j) boff[j] = (colb + j * 16 + r) * 128;

  const int nsteps = K >> 6;
  stage(0, 0);
  int cur = 0;
  for (int it = 0; it < nsteps; ++it) {
    if (it + 1 < nsteps) {
      stage(cur ^ 1, (it + 1) << 6);
      if constexpr (BN == 128) asm volatile("s_waitcnt vmcnt(4)" ::: "memory");
      else                     asm volatile("s_waitcnt vmcnt(3)" ::: "memory");
    } else {
      asm volatile("s_waitcnt vmcnt(0)" ::: "memory");
    }
    __builtin_amdgcn_s_barrier();           // buf[cur] landed for all waves
    __builtin_amdgcn_sched_barrier(0);
    const char* pa = lds + cur * BUF;
    const char* pb = pa + ABYT;
    #pragma unroll
    for (int s = 0; s < 2; ++s) {
      const int gso = s ? gs1 : gs0;
      bf16x8 af[MI], bv[NI];
      #pragma unroll
      for (int i = 0; i < MI; ++i) af[i] = *(const bf16x8*)(pa + aoff[i] + gso);
      #pragma unroll
      for (int j = 0; j < NI; ++j) bv[j] = *(const bf16x8*)(pb + boff[j] + gso);
      #pragma unroll
      for (int i = 0; i < MI; ++i)
        #pragma unroll
        for (int j = 0; j < NI; ++j)
          acc[i][j] = __builtin_amdgcn_mfma_f32_16x16x32_bf16(af[i], bv[j], acc[i][j], 0, 0, 0);
    }
    asm volatile("s_waitcnt lgkmcnt(0)" ::: "memory");  // this wave's ds_reads done
    __builtin_amdgcn_sched_barrier(0);
    __builtin_amdgcn_s_barrier();           // safe to overwrite buf[cur]
    cur ^= 1;
  }

  const int fr = lane & 15, fq = lane >> 4;
  #pragma unroll
  for (int i = 0; i < MI; ++i) {
    const int r0 = bm + rowb + i * 16 + fq * 4;
    #pragma unroll
    for (int j = 0; j < NI; ++j) {
      const int cn = bn + colb + j * 16 + fr;
      const float bvv = bias ? bias[cn] : 0.f;
      float vv[4];
      #pragma unroll
      for (int t = 0; t < 4; ++t) {
        float v = acc[i][j][t] + bvv;
        if (rowscale) v *= rowscale[r0 + t];
        if (act) v = 0.5f * v * (1.f + tanhf(0.7978845608028654f * (v + 0.044715f * v * v * v)));
        vv[t] = v;
      }
      if (outF) {
        #pragma unroll
        for (int t = 0; t < 4; ++t) outF[cof + (long long)(r0 + t) * ldc + cn] = vv[t];
      }
      if (outB) {
        #pragma unroll
        for (int t = 0; t < 4; ++t) outB[cof + (long long)(r0 + t) * ldc + cn] = f2bf(vv[t]);
      }
      if (outBT) {
        u16x4 pk = {f2bf(vv[0]), f2bf(vv[1]), f2bf(vv[2]), f2bf(vv[3])};
        *(u16x4*)(outBT + tof + (long long)cn * ldt + r0) = pk;
      }
    }
  }
}

// ---------------- transpose + convert: in[R][C] fp32 -> out[C][R] bf16 ----------------
__global__ __launch_bounds__(256)
void k_tcvt(const float* __restrict__ in, u16* __restrict__ out, int R, int C)
{
  __shared__ float t[32][33];
  const int bx = blockIdx.x * 32, by = blockIdx.y * 32;
  const int tx = threadIdx.x & 31, ty = threadIdx.x >> 5;
  #pragma unroll
  for (int i = 0; i < 32; i += 8)
    t[ty + i][tx] = in[(long long)(by + ty + i) * C + bx + tx];
  __syncthreads();
  #pragma unroll
  for (int i = 0; i < 32; i += 8)
    out[(long long)(bx + ty + i) * R + by + tx] = f2bf(t[tx][ty + i]);
}

// ---------------- convert fp32 -> bf16 ----------------
__global__ __launch_bounds__(256)
void k_cvt(const float* __restrict__ in, u16* __restrict__ out, int n)
{
  int i = blockIdx.x * 256 + threadIdx.x;
  if (i < n) out[i] = f2bf(in[i]);
}

// ---------------- row softmax on bf16 in place (cols <= 1024) ----------------
__global__ __launch_bounds__(256)
void k_softmax_b16(u16* __restrict__ x, int cols, float scale)
{
  u16* p = x + (long long)blockIdx.x * cols;
  const int tid = threadIdx.x;
  __shared__ float red[256];
  float v[4];
  float m = -1e30f;
  #pragma unroll
  for (int i = 0; i < 4; ++i) {
    const int c = tid + (i << 8);
    v[i] = (c < cols) ? bf2f(p[c]) * scale : -1e30f;
    m = fmaxf(m, v[i]);
  }
  red[tid] = m; __syncthreads();
  for (int s = 128; s > 0; s >>= 1) { if (tid < s) red[tid] = fmaxf(red[tid], red[tid + s]); __syncthreads(); }
  m = red[0]; __syncthreads();
  float sum = 0.f;
  #pragma unroll
  for (int i = 0; i < 4; ++i) { v[i] = expf(v[i] - m); sum += v[i]; }
  red[tid] = sum; __syncthreads();
  for (int s = 128; s > 0; s >>= 1) { if (tid < s) red[tid] += red[tid + s]; __syncthreads(); }
  const float inv = 1.f / red[0];
  #pragma unroll
  for (int i = 0; i < 4; ++i) {
    const int c = tid + (i << 8);
    if (c < cols) p[c] = f2bf(v[i] * inv);
  }
}

// ---------------- layernorm: LN(x [+res])*g + b -> fp32 out (opt) + bf16 out (opt) ----------------
__global__ __launch_bounds__(256)
void k_layernorm(const float* __restrict__ x, const float* __restrict__ res,
                 const float* __restrict__ g, const float* __restrict__ b,
                 float* __restrict__ outF, u16* __restrict__ outB, int cols)
{
  const long long ro = (long long)blockIdx.x * cols;
  const float* px = x + ro;
  const float* pr = res ? res + ro : nullptr;
  __shared__ float red[256];
  const int tid = threadIdx.x;
  float s = 0.f;
  for (int c = tid; c < cols; c += 256) { float v = px[c] + (pr ? pr[c] : 0.f); s += v; }
  red[tid] = s; __syncthreads();
  for (int t = 128; t > 0; t >>= 1) { if (tid < t) red[tid] += red[tid + t]; __syncthreads(); }
  const float mean = red[0] / cols; __syncthreads();
  float s2 = 0.f;
  for (int c = tid; c < cols; c += 256) { float v = px[c] + (pr ? pr[c] : 0.f) - mean; s2 += v * v; }
  red[tid] = s2; __syncthreads();
  for (int t = 128; t > 0; t >>= 1) { if (tid < t) red[tid] += red[tid + t]; __syncthreads(); }
  const float inv = rsqrtf(red[0] / cols + 1e-5f);
  for (int c = tid; c < cols; c += 256) {
    float v = (px[c] + (pr ? pr[c] : 0.f) - mean) * inv * g[c] + b[c];
    if (outF) outF[ro + c] = v;
    if (outB) outB[ro + c] = f2bf(v);
  }
}

// ---------------- gate[row] = sigmoid(dot(x[row], w) + b0), 1 wave / row ----------------
__global__ __launch_bounds__(256)
void k_gate(const float* __restrict__ x, const float* __restrict__ w,
            const float* __restrict__ b0, float* __restrict__ out, int cols)
{
  const int lane = threadIdx.x & 63;
  const int wv = threadIdx.x >> 6;
  const long long row = (long long)blockIdx.x * 4 + wv;
  const float* p = x + row * cols;
  float s = 0.f;
  for (int c = lane; c < cols; c += 64) s += p[c] * w[c];
  #pragma unroll
  for (int off = 32; off > 0; off >>= 1) s += __shfl_down(s, off);
  if (lane == 0) out[row] = 1.0f / (1.0f + expf(-(s + b0[0])));
}

// ---------------- elementwise ----------------
__global__ __launch_bounds__(256)
void k_combine2(float* __restrict__ oF, u16* __restrict__ oB,
                const float* __restrict__ a, float sa, const float* __restrict__ b,
                const float* __restrict__ emb, int n, int Dm1)
{
  int i = blockIdx.x * 256 + threadIdx.x;
  if (i >= n) return;
  float v = sa * a[i];
  if (b) v += b[i];
  v += emb[i & Dm1];
  oF[i] = v; oB[i] = f2bf(v);
}

__global__ __launch_bounds__(256)
void k_gated_add(float* __restrict__ out, const float* __restrict__ h,
                 const float* __restrict__ r, const float* __restrict__ gate, int n, int Dv)
{
  int i = blockIdx.x * 256 + threadIdx.x;
  if (i >= n) return;
  out[i] = h[i] + gate[i / Dv] * r[i];
}

__global__ __launch_bounds__(256)
void k_add2(float* __restrict__ oF, u16* __restrict__ oB,
            const float* __restrict__ a, const float* __restrict__ b, int n)
{
  int i = blockIdx.x * 256 + threadIdx.x;
  if (i >= n) return;
  float v = a[i] + b[i];
  oF[i] = v; oB[i] = f2bf(v);
}

// ---------------- host ----------------
extern "C" void kernel_launch(void* const* d_in, const int* in_sizes, int n_in,
                              void* d_out, int out_size, void* d_ws, size_t ws_size,
                              hipStream_t stream)
{
  (void)in_sizes; (void)n_in; (void)out_size;
  const float* x        = (const float*)d_in[0];
  const float* cache0   = (const float*)d_in[1];
  const float* iter_emb = (const float*)d_in[2];
  const float* rq_w     = (const float*)d_in[3];
  const float* rg_w     = (const float*)d_in[4];
  const float* rg_b     = (const float*)d_in[5];
  const float* ck_w     = (const float*)d_in[6];
  const float* cv_w     = (const float*)d_in[7];
  const float* aq_w     = (const float*)d_in[8];
  const float* ak_w     = (const float*)d_in[9];
  const float* av_w     = (const float*)d_in[10];
  const float* ao_w     = (const float*)d_in[11];
  const float* aq_b     = (const float*)d_in[12];
  const float* ak_b     = (const float*)d_in[13];
  const float* av_b     = (const float*)d_in[14];
  const float* ao_b     = (const float*)d_in[15];
  const float* f1_w     = (const float*)d_in[16];
  const float* f1_b     = (const float*)d_in[17];
  const float* f2_w     = (const float*)d_in[18];
  const float* f2_b     = (const float*)d_in[19];
  const float* n1_g     = (const float*)d_in[20];
  const float* n1_b     = (const float*)d_in[21];
  const float* n2_g     = (const float*)d_in[22];
  const float* n2_b     = (const float*)d_in[23];
  const float* sq_w     = (const float*)d_in[24];
  const float* tk_w     = (const float*)d_in[25];
  const float* tv_w     = (const float*)d_in[26];
  const float* wg_w     = (const float*)d_in[27];
  const float* wg_b     = (const float*)d_in[28];
  const float* cq_w     = (const float*)d_in[29];
  const float* ck2_w    = (const float*)d_in[30];
  const float* cv2_w    = (const float*)d_in[31];
  const float* co_w     = (const float*)d_in[32];
  const float* cq_b     = (const float*)d_in[33];
  const float* ck2_b    = (const float*)d_in[34];
  const float* cv2_b    = (const float*)d_in[35];
  const float* co_b     = (const float*)d_in[36];
  const float* cn_g     = (const float*)d_in[37];
  const float* cn_b     = (const float*)d_in[38];
  // d_in[39] = max_iterations (fixed 2; schedule hardcoded for graph capture)

  float* out = (float*)d_out;

  // -------- workspace carve --------
  size_t off = 0;
  char* base = (char*)d_ws;
  auto allocF = [&](size_t n) { float* p = (float*)(base + off); off += n * 4; off = (off + 255) & ~(size_t)255; return p; };
  auto allocH = [&](size_t n) { u16* p = (u16*)(base + off); off += n * 2; off = (off + 255) & ~(size_t)255; return p; };

  float* hbuf  = allocF((size_t)BS_ * D_);
  float* henh  = allocF((size_t)BS_ * D_);
  float* hcomp = allocF((size_t)BS_ * D_);
  float* h2b   = allocF((size_t)BS_ * D_);
  float* tA    = allocF((size_t)BS_ * D_);
  float* gate  = allocF((size_t)BS_);
  float* ccnf  = allocF((size_t)BNS_ * DS_);
  float* updf  = allocF((size_t)BNS_ * DS_);
  float* coo   = allocF((size_t)BNS_ * DS_);
  float* ccwf  = allocF((size_t)BNS_ * DS_);
  u16* rqT  = allocH((size_t)D_ * D_);
  u16* ckT  = allocH((size_t)D_ * DS_);
  u16* cvT  = allocH((size_t)D_ * DS_);
  u16* aqT  = allocH((size_t)D_ * D_);
  u16* akT  = allocH((size_t)D_ * D_);
  u16* avT  = allocH((size_t)D_ * D_);
  u16* aoT  = allocH((size_t)D_ * D_);
  u16* f1T  = allocH((size_t)DFF_ * D_);
  u16* f2T  = allocH((size_t)D_ * DFF_);
  u16* sqT  = allocH((size_t)DS_ * DS_);
  u16* tkT  = allocH((size_t)DS_ * D_);
  u16* tvTw = allocH((size_t)DS_ * D_);
  u16* cqT  = allocH((size_t)DS_ * DS_);
  u16* ck2T = allocH((size_t)DS_ * DS_);
  u16* cv2T = allocH((size_t)DS_ * DS_);
  u16* coT  = allocH((size_t)DS_ * DS_);
  u16* bb1  = allocH((size_t)BS_ * D_);
  u16* bb2  = allocH((size_t)BS_ * D_);
  u16* bb3  = allocH((size_t)BS_ * D_);
  u16* bb4  = allocH((size_t)BS_ * D_);
  u16* bb5  = allocH((size_t)B_ * H_ * S_ * S_);
  u16* cc0b = allocH((size_t)BNS_ * DS_);
  u16* ccwb = allocH((size_t)BNS_ * DS_);
  u16* sqb  = allocH((size_t)BNS_ * DS_);
  u16* tkb  = allocH((size_t)BS_ * DS_);
  u16* tvTb = allocH((size_t)DS_ * BS_);
  u16* ccnb = allocH((size_t)BNS_ * DS_);
  u16* cqb  = allocH((size_t)BNS_ * DS_);
  u16* ck2b = allocH((size_t)BNS_ * DS_);
  u16* cv2Tb= allocH((size_t)DS_ * BNS_);
  u16* csab = allocH((size_t)BNS_ * DS_);
  if (off > ws_size) return;

  auto gemm = [&](int M, int N, int K, int z, int zdiv,
                  const u16* Ap, int lda, long long sa, long long sa2,
                  const u16* Bq, int ldb, long long sb, long long sb2,
                  float* oF, u16* oB, int ldc, long long sc, long long sc2,
                  u16* oBT, int ldt, long long st, long long st2,
                  const float* bias, const float* rsc, int act) {
    const long long blocks128 = (N % 128 == 0) ? (long long)(N / 128) * (M / 128) * z : 0;
    if (N % 128 == 0 && blocks128 >= 256) {
      dim3 g(N / 128, M / 128, z);
      k_gemm<128><<<g, 512, 0, stream>>>(Ap, lda, sa, sa2, Bq, ldb, sb, sb2,
          oF, oB, ldc, sc, sc2, oBT, ldt, st, st2, K, zdiv, bias, rsc, act);
    } else {
      dim3 g(N / 64, M / 128, z);
      k_gemm<64><<<g, 512, 0, stream>>>(Ap, lda, sa, sa2, Bq, ldb, sb, sb2,
          oF, oB, ldc, sc, sc2, oBT, ldt, st, st2, K, zdiv, bias, rsc, act);
    }
  };
  auto tcvt = [&](const float* in, u16* o, int R, int C) {
    dim3 g(C / 32, R / 32);
    k_tcvt<<<g, 256, 0, stream>>>(in, o, R, C);
  };
  auto lnorm = [&](const float* xp, const float* rp, const float* g, const float* b,
                   float* oF, u16* oB, int rows, int cols) {
    k_layernorm<<<rows, 256, 0, stream>>>(xp, rp, g, b, oF, oB, cols);
  };
  auto eg = [](int n) { return dim3((n + 255) / 256); };

  // ---- weight prep ----
  tcvt(rq_w, rqT, D_, D_);
  tcvt(ck_w, ckT, DS_, D_);
  tcvt(cv_w, cvT, DS_, D_);
  tcvt(aq_w, aqT, D_, D_);
  tcvt(ak_w, akT, D_, D_);
  tcvt(av_w, avT, D_, D_);
  tcvt(ao_w, aoT, D_, D_);
  tcvt(f1_w, f1T, D_, DFF_);
  tcvt(f2_w, f2T, DFF_, D_);
  tcvt(sq_w, sqT, DS_, DS_);
  tcvt(tk_w, tkT, D_, DS_);
  tcvt(tv_w, tvTw, D_, DS_);
  tcvt(cq_w, cqT, DS_, DS_);
  tcvt(ck2_w, ck2T, DS_, DS_);
  tcvt(cv2_w, cv2T, DS_, DS_);
  tcvt(co_w, coT, DS_, DS_);
  k_cvt<<<eg(BNS_ * DS_), 256, 0, stream>>>(cache0, cc0b, BNS_ * DS_);

  // ---- mem_read ----
  auto mem_read = [&](const float* h_f, const u16* h_b, const u16* cc_b, float* o_henh) {
    gemm(BS_, D_, D_, 1, 1, h_b, D_, 0, 0, rqT, D_, 0, 0,
         nullptr, bb2, D_, 0, 0, nullptr, 0, 0, 0, nullptr, nullptr, 0);            // q
    gemm(BNS_, D_, DS_, 1, 1, cc_b, DS_, 0, 0, ckT, DS_, 0, 0,
         nullptr, bb3, D_, 0, 0, nullptr, 0, 0, 0, nullptr, nullptr, 0);            // k
    gemm(BNS_, D_, DS_, 1, 1, cc_b, DS_, 0, 0, cvT, DS_, 0, 0,
         nullptr, nullptr, 0, 0, 0, bb4, BNS_, 0, 0, nullptr, nullptr, 0);          // v^T
    gemm(S_, NSLOT_, D_, B_, 1, bb2, D_, (long long)S_ * D_, 0,
         bb3, D_, (long long)NSLOT_ * D_, 0,
         nullptr, bb5, NSLOT_, (long long)S_ * NSLOT_, 0,
         nullptr, 0, 0, 0, nullptr, nullptr, 0);                                    // q k^T
    k_softmax_b16<<<B_ * S_, 256, 0, stream>>>(bb5, NSLOT_, 0.03125f);
    gemm(S_, D_, NSLOT_, B_, 1, bb5, NSLOT_, (long long)S_ * NSLOT_, 0,
         bb4, BNS_, NSLOT_, 0,
         tA, nullptr, D_, (long long)S_ * D_, 0,
         nullptr, 0, 0, 0, nullptr, nullptr, 0);                                    // readout
    k_gate<<<BS_ / 4, 256, 0, stream>>>(h_f, rg_w, rg_b, gate, D_);
    k_gated_add<<<eg(BS_ * D_), 256, 0, stream>>>(o_henh, h_f, tA, gate, BS_ * D_, D_);
  };

  // ---- compute_block ----
  auto compute_block = [&](const float* he, float* oF, u16* oB) {
    lnorm(he, nullptr, n1_g, n1_b, nullptr, bb1, BS_, D_);
    gemm(BS_, D_, D_, 1, 1, bb1, D_, 0, 0, aqT, D_, 0, 0,
         nullptr, bb2, D_, 0, 0, nullptr, 0, 0, 0, aq_b, nullptr, 0);               // qa
    gemm(BS_, D_, D_, 1, 1, bb1, D_, 0, 0, akT, D_, 0, 0,
         nullptr, bb3, D_, 0, 0, nullptr, 0, 0, 0, ak_b, nullptr, 0);               // ka
    gemm(BS_, D_, D_, 1, 1, bb1, D_, 0, 0, avT, D_, 0, 0,
         nullptr, nullptr, 0, 0, 0, bb4, BS_, 0, 0, av_b, nullptr, 0);              // va^T
    gemm(S_, S_, HD_, B_ * H_, H_,
         bb2, D_, (long long)S_ * D_, HD_,
         bb3, D_, (long long)S_ * D_, HD_,
         nullptr, bb5, S_, (long long)H_ * S_ * S_, (long long)S_ * S_,
         nullptr, 0, 0, 0, nullptr, nullptr, 0);                                    // scores
    k_softmax_b16<<<B_ * H_ * S_, 256, 0, stream>>>(bb5, S_, 0.0625f);
    gemm(S_, HD_, S_, B_ * H_, H_,
         bb5, S_, (long long)H_ * S_ * S_, (long long)S_ * S_,
         bb4, BS_, S_, (long long)HD_ * BS_,
         nullptr, bb2, D_, (long long)S_ * D_, HD_,
         nullptr, 0, 0, 0, nullptr, nullptr, 0);                                    // attnv
    gemm(BS_, D_, D_, 1, 1, bb2, D_, 0, 0, aoT, D_, 0, 0,
         tA, nullptr, D_, 0, 0, nullptr, 0, 0, 0, ao_b, nullptr, 0);                // attno
    lnorm(he, tA, n1_g, n1_b, h2b, bb1, BS_, D_);
    gemm(BS_, DFF_, D_, 1, 1, bb1, D_, 0, 0, f1T, D_, 0, 0,
         nullptr, bb5, DFF_, 0, 0, nullptr, 0, 0, 0, f1_b, nullptr, 1);             // f1+gelu
    gemm(BS_, D_, DFF_, 1, 1, bb5, DFF_, 0, 0, f2T, DFF_, 0, 0,
         tA, nullptr, D_, 0, 0, nullptr, 0, 0, 0, f2_b, nullptr, 0);                // f2
    lnorm(h2b, tA, n2_g, n2_b, oF, oB, BS_, D_);
  };

  // ---- mem_write + cache self-attn (skipped in last iter) ----
  auto mem_write_csa = [&](const float* hc_f, const u16* hc_b,
                           const float* ccin_f, const u16* ccin_b) {
    gemm(BNS_, DS_, DS_, 1, 1, ccin_b, DS_, 0, 0, sqT, DS_, 0, 0,
         nullptr, sqb, DS_, 0, 0, nullptr, 0, 0, 0, nullptr, nullptr, 0);           // sq
    gemm(BS_, DS_, D_, 1, 1, hc_b, D_, 0, 0, tkT, D_, 0, 0,
         nullptr, tkb, DS_, 0, 0, nullptr, 0, 0, 0, nullptr, nullptr, 0);           // tk
    k_gate<<<BS_ / 4, 256, 0, stream>>>(hc_f, wg_w, wg_b, gate, D_);
    gemm(BS_, DS_, D_, 1, 1, hc_b, D_, 0, 0, tvTw, D_, 0, 0,
         nullptr, nullptr, 0, 0, 0, tvTb, BS_, 0, 0, nullptr, gate, 0);             // (gate*tv)^T
    gemm(NSLOT_, S_, DS_, B_, 1, sqb, DS_, (long long)NSLOT_ * DS_, 0,
         tkb, DS_, (long long)S_ * DS_, 0,
         nullptr, bb5, S_, (long long)NSLOT_ * S_, 0,
         nullptr, 0, 0, 0, nullptr, nullptr, 0);                                    // slot scores
    k_softmax_b16<<<B_ * NSLOT_, 256, 0, stream>>>(bb5, S_, 0.05590169943749474f);
    gemm(NSLOT_, DS_, S_, B_, 1, bb5, S_, (long long)NSLOT_ * S_, 0,
         tvTb, BS_, S_, 0,
         updf, nullptr, DS_, (long long)NSLOT_ * DS_, 0,
         nullptr, 0, 0, 0, nullptr, nullptr, 0);                                    // upd
    k_add2<<<eg(BNS_ * DS_), 256, 0, stream>>>(ccnf, ccnb, ccin_f, updf, BNS_ * DS_);
    gemm(BNS_, DS_, DS_, 1, 1, ccnb, DS_, 0, 0, cqT, DS_, 0, 0,
         nullptr, cqb, DS_, 0, 0, nullptr, 0, 0, 0, cq_b, nullptr, 0);              // cq
    gemm(BNS_, DS_, DS_, 1, 1, ccnb, DS_, 0, 0, ck2T, DS_, 0, 0,
         nullptr, ck2b, DS_, 0, 0, nullptr, 0, 0, 0, ck2_b, nullptr, 0);            // ck
    gemm(BNS_, DS_, DS_, 1, 1, ccnb, DS_, 0, 0, cv2T, DS_, 0, 0,
         nullptr, nullptr, 0, 0, 0, cv2Tb, BNS_, 0, 0, cv2_b, nullptr, 0);          // cv^T
    gemm(NSLOT_, NSLOT_, CHD_, B_ * CH_, CH_,
         cqb, DS_, (long long)NSLOT_ * DS_, CHD_,
         ck2b, DS_, (long long)NSLOT_ * DS_, CHD_,
         nullptr, bb5, NSLOT_, (long long)CH_ * NSLOT_ * NSLOT_, (long long)NSLOT_ * NSLOT_,
         nullptr, 0, 0, 0, nullptr, nullptr, 0);                                    // csa scores
    k_softmax_b16<<<B_ * CH_ * NSLOT_, 256, 0, stream>>>(bb5, NSLOT_, 0.125f);
    gemm(NSLOT_, CHD_, NSLOT_, B_ * CH_, CH_,
         bb5, NSLOT_, (long long)CH_ * NSLOT_ * NSLOT_, (long long)NSLOT_ * NSLOT_,
         cv2Tb, BNS_, NSLOT_, (long long)CHD_ * BNS_,
         nullptr, csab, DS_, (long long)NSLOT_ * DS_, CHD_,
         nullptr, 0, 0, 0, nullptr, nullptr, 0);                                    // csa pv
    gemm(BNS_, DS_, DS_, 1, 1, csab, DS_, 0, 0, coT, DS_, 0, 0,
         coo, nullptr, DS_, 0, 0, nullptr, 0, 0, 0, co_b, nullptr, 0);              // co
    lnorm(ccnf, coo, cn_g, cn_b, ccwf, ccwb, BNS_, DS_);
  };

  // ================= iteration 0 =================
  k_combine2<<<eg(BS_ * D_), 256, 0, stream>>>(hbuf, bb1, x, 1.0f, nullptr, iter_emb, BS_ * D_, D_ - 1);
  mem_read(hbuf, bb1, cc0b, henh);
  compute_block(henh, hcomp, bb3);
  mem_write_csa(hcomp, bb3, cache0, cc0b);

  // ================= iteration 1 (last: cache update dead, skipped) =================
  k_combine2<<<eg(BS_ * D_), 256, 0, stream>>>(hbuf, bb1, hcomp, 2.0f, x, iter_emb + D_, BS_ * D_, D_ - 1);
  mem_read(hbuf, bb1, ccwb, henh);
  compute_block(henh, out, nullptr);
}